// Round 22
// baseline (442.360 us; speedup 1.0000x reference)
//
#include <hip/hip_runtime.h>
#include <math.h>

// Problem constants: B=8, C=512, H=W=32, N=1024, G=256, R=9
using half8 = __attribute__((ext_vector_type(8))) _Float16;
using half4 = __attribute__((ext_vector_type(4))) _Float16;
using f32x4 = __attribute__((ext_vector_type(4))) float;

// Workspace layout (f32 slots)
static constexpr size_t OFF_WGCH  = 0;           // 3*4608*512 halfs
static constexpr size_t OFF_COEF  = 7077888;     // rowsum (18432 f32)
static constexpr size_t OFF_COEFH = 11796480;    // 4718592 halfs
static constexpr size_t OFF_X     = 16515072;    // 1048576 f32
static constexpr size_t OFF_CNTI  = 17565696;    // 2048 int
static constexpr size_t OFF_LISTS = 17567744;    // 98304 int
static constexpr size_t OFF_CSRO  = 17666048;    // 2049 int (pad to 2304)
static constexpr size_t OFF_CSRV  = 17668352;    // 8192 u16
static constexpr size_t OFF_W1H   = 17672960;    // 3*512*512 halfs
static constexpr size_t OFF_W2H   = 18459392;
static constexpr size_t OFF_CWH   = 19245824;    // 512*1024 halfs
static constexpr size_t OFF_XH    = 19770112;    // 2048*512 halfs
static constexpr size_t OFF_HH    = 20818688;
static constexpr size_t OFF_BIG   = 21867264;    // 18874368 f32 region
static constexpr size_t OFF_GA    = 40741632;    // 4718592 f32 (gaT); h1/h2 alias
static constexpr size_t OFF_H1    = OFF_GA;      // 1048576 halfs
static constexpr size_t OFF_H2    = OFF_GA + 1048576;

// Direct global->LDS DMA, 16 B per lane. LDS dest = wave-uniform base + lane*16.
__device__ inline void gll16(const void* g, void* l) {
  __builtin_amdgcn_global_load_lds(
      (__attribute__((address_space(1))) void*)(size_t)g,
      (__attribute__((address_space(3))) void*)(size_t)l, 16, 0, 0);
}

// Counted-vmcnt barrier.
#define VM_BAR(N) asm volatile("s_waitcnt vmcnt(" #N ")\ns_barrier" ::: "memory")

// ---------------------------------------------------------------------------
__global__ __launch_bounds__(256) void k_lists(const int* __restrict__ gl,
                                               int* __restrict__ cntI,
                                               int* __restrict__ lists) {
  int idx = blockIdx.x * 256 + threadIdx.x;  // 8192
  int b = idx >> 10, n = idx & 1023;
  int h = gl[idx];
  int pos = atomicAdd(&cntI[b * 256 + h], 1);
  if (pos < 48) lists[(b * 256 + h) * 48 + pos] = n;
}

// Build CSR: csr_off[2049] (int), csr_val (u16 n-indices grouped by bg)
__global__ __launch_bounds__(256) void k_csr(const int* __restrict__ cntI,
                                             const int* __restrict__ lists,
                                             int* __restrict__ csr_off,
                                             unsigned short* __restrict__ csr_val) {
  __shared__ int wsum[256];
  __shared__ int tot[257];
  int t = threadIdx.x;
  int base = t * 8;
  int loc[8]; int s = 0;
#pragma unroll
  for (int i = 0; i < 8; ++i) {
    int c = cntI[base + i]; if (c > 48) c = 48;
    loc[i] = s; s += c;
  }
  wsum[t] = s;
  __syncthreads();
  if (t == 0) {
    int a = 0;
    for (int i = 0; i < 256; ++i) { tot[i] = a; a += wsum[i]; }
    tot[256] = a;
  }
  __syncthreads();
  int off0 = tot[t];
#pragma unroll
  for (int i = 0; i < 8; ++i) {
    int bg = base + i;
    int o = off0 + loc[i];
    csr_off[bg] = o;
    int c = cntI[bg]; if (c > 48) c = 48;
    for (int j = 0; j < c; ++j)
      csr_val[o + j] = (unsigned short)(lists[bg * 48 + j] & 1023);
  }
  if (t == 0) csr_off[2048] = tot[256];
}

// ---------------------------------------------------------------------------
// Merged front-end, latency-bound branches FIRST (dispatch order ~ ascending
// blockIdx, so t2ga/pool start immediately and overlap the wg BW stream):
//   blocks [0,2048):       t2ga gather (gaT)
//   blocks [2048,2560):    pool via CSR (x, xh)
//   blocks [2560,9472):    wg collapse (float4/thread, fp16 out)
//   blocks [9472,17664):   w1/w2/cw fp16 cast
__global__ __launch_bounds__(256) void k_front(const float* __restrict__ wg,
                                               const float* __restrict__ w1,
                                               const float* __restrict__ w2,
                                               const float* __restrict__ cw,
                                               _Float16* __restrict__ wgh,
                                               _Float16* __restrict__ w1h,
                                               _Float16* __restrict__ w2h,
                                               _Float16* __restrict__ cwh,
                                               const float* __restrict__ adj,
                                               const int* __restrict__ cntI,
                                               const int* __restrict__ lists,
                                               float* __restrict__ gaT,
                                               const float* __restrict__ inp,
                                               const int* __restrict__ csr_off,
                                               const unsigned short* __restrict__ csr_val,
                                               float* __restrict__ x,
                                               _Float16* __restrict__ xh) {
  __shared__ __align__(16) char smem[37120];
  int bid = blockIdx.x;
  int t = threadIdx.x;
  if (bid < 2048) {
    // ---- t2ga: gaT[b,r,h,g] = sum_{m in g} sum_{n in h} adj[r,n,m] ----
    float (*ul)[1024] = (float(*)[1024])smem;          // 9*1024*4 = 36864 B
    int* lsh = (int*)(smem + 36864);                   // 48*4 = 192 B
    int b = bid >> 8, h = bid & 255;
    int cnt = cntI[b * 256 + h]; if (cnt > 48) cnt = 48;
    if (t < cnt) lsh[t] = lists[(b * 256 + h) * 48 + t];
    __syncthreads();
    float u[9][4];
#pragma unroll
    for (int r = 0; r < 9; ++r)
#pragma unroll
      for (int j = 0; j < 4; ++j) u[r][j] = 0.f;
    for (int i = 0; i < cnt; ++i) {
      const float* base = adj + ((size_t)lsh[i] << 10) + t;
#pragma unroll
      for (int r = 0; r < 9; ++r) {
        const float* p = base + (size_t)r * 1048576;
        u[r][0] += p[0];
        u[r][1] += p[256];
        u[r][2] += p[512];
        u[r][3] += p[768];
      }
    }
#pragma unroll
    for (int r = 0; r < 9; ++r)
#pragma unroll
      for (int j = 0; j < 4; ++j) ul[r][j * 256 + t] = u[r][j];
    __syncthreads();
    int g = t;
    int cg = cntI[b * 256 + g]; if (cg > 48) cg = 48;
    const int* lg = lists + (b * 256 + g) * 48;
    float s[9];
#pragma unroll
    for (int r = 0; r < 9; ++r) s[r] = 0.f;
    for (int i = 0; i < cg; ++i) {
      int m = lg[i];
#pragma unroll
      for (int r = 0; r < 9; ++r) s[r] += ul[r][m];
    }
#pragma unroll
    for (int r = 0; r < 9; ++r)
      gaT[(((size_t)(b * 9 + r)) * 256 + h) * 256 + g] = s[r];
  } else if (bid < 2560) {
    // ---- pool via CSR; emits x (f32) and fp16 cast ----
    float (*rows)[1032] = (float(*)[1032])smem;        // 8*1032*4 = 33024 B
    int* offs = (int*)(smem + 33024);                  // 257*4 = 1028 B
    unsigned short* vals = (unsigned short*)(smem + 33024 + 1028);  // 2048 B
    int blk = bid - 2048;
    int b = blk >> 6, cch = blk & 63;
    const float4* src = (const float4*)(inp + (size_t)b * 524288 + (size_t)cch * 8 * 1024);
    for (int k = t; k < 2048; k += 256) {
      float4 v = src[k];
      int c = k >> 8;
      int m = (k & 255) << 2;
      *(float4*)&rows[c][m] = v;
    }
    for (int k = t; k < 257; k += 256) offs[k] = csr_off[b * 256 + k];
    __syncthreads();
    int vbase = offs[0];
    int nv = offs[256] - vbase;
    for (int k = t; k < nv; k += 256) vals[k] = csr_val[vbase + k];
    __syncthreads();
    int g = t;
    int o0 = offs[g] - vbase, o1 = offs[g + 1] - vbase;
    float s[8] = {0.f, 0.f, 0.f, 0.f, 0.f, 0.f, 0.f, 0.f};
    for (int i = o0; i < o1; ++i) {
      int n = vals[i];
#pragma unroll
      for (int c = 0; c < 8; ++c) s[c] += rows[c][n];
    }
    const float sc = 1.0f / (1.0f + 1e-7f);
    size_t xbase = ((size_t)b * 256 + g) * 512 + cch * 8;
#pragma unroll
    for (int c = 0; c < 8; ++c) {
      float v = s[c] * sc;
      x[xbase + c] = v;
      xh[xbase + c] = (_Float16)v;
    }
  } else if (bid < 9472) {
    // ---- wg collapse (float4/thread, fp16 out) ----
    size_t idx = (size_t)(bid - 2560) * 256 + t;   // 1769472 float4s
    size_t i = idx / (4608u * 128u);
    size_t rem = idx % (4608u * 128u);
    size_t j = rem / 128u, c4 = rem % 128u;
    const float* p = wg + i * 21233664ull + j * 4608ull + c4 * 4;
    float4 s = {0.f, 0.f, 0.f, 0.f};
#pragma unroll
    for (int r = 0; r < 9; ++r) {
      float4 v = *(const float4*)(p + r * 512);
      s.x += v.x; s.y += v.y; s.z += v.z; s.w += v.w;
    }
    half4 hv;
    hv[0] = (_Float16)s.x; hv[1] = (_Float16)s.y;
    hv[2] = (_Float16)s.z; hv[3] = (_Float16)s.w;
    *(half4*)&wgh[idx * 4] = hv;
  } else {
    // ---- w1/w2/cw fp16 cast ----
    size_t idx = (size_t)(bid - 9472) * 256 + t;   // 2097152 total
    if (idx < 786432) {
      w1h[idx] = (_Float16)w1[idx];
    } else if (idx < 1572864) {
      size_t o = idx - 786432;
      w2h[o] = (_Float16)w2[o];
    } else {
      size_t o = idx - 1572864;
      cwh[o] = (_Float16)cw[o];
    }
  }
}

// rowsum[z,g] = sum_h gaT[z,h,g]
__global__ __launch_bounds__(256) void k_gasum(const float* __restrict__ gaT,
                                               float* __restrict__ rowsum) {
  int z = blockIdx.x;            // 72
  int t = threadIdx.x;           // g
  const float* p = gaT + ((size_t)z * 256) * 256 + t;
  float s = 0.f;
  for (int h = 0; h < 256; ++h) s += p[(size_t)h * 256];
  rowsum[z * 256 + t] = s;
}

// coef via 64x64 LDS transpose tiles; fp16.
__global__ __launch_bounds__(256) void k_coef_t(const float* __restrict__ gaT,
                                                const float* __restrict__ rowsum,
                                                _Float16* __restrict__ chi) {
  __shared__ float tl[64][65];
  __shared__ float tlf[64][65];
  __shared__ float rs[64];
  int t = threadIdx.x;
  int z = blockIdx.y;            // b*9+r
  int b = z / 9, r = z % 9;
  int tile = blockIdx.x;         // 16
  int h0 = (tile & 3) * 64, g0 = (tile >> 2) * 64;
  size_t base  = ((size_t)z * 256 + h0) * 256 + g0;
  size_t baseF = ((size_t)((7 - b) * 9 + r) * 256 + h0) * 256 + g0;
  for (int k = t; k < 4096; k += 256) {
    int i = k >> 6, j = k & 63;
    tl[i][j]  = gaT[base  + (size_t)i * 256 + j];
    tlf[i][j] = gaT[baseF + (size_t)i * 256 + j];
  }
  if (t < 64) rs[t] = rowsum[z * 256 + g0 + t] + 1.0f;
  __syncthreads();
  for (int k = t; k < 4096; k += 256) {
    int i2 = k >> 6, j2 = k & 63;        // i2: g-local, j2: h-local
    float v = tl[j2][i2], vf = tlf[j2][i2];
    float num = (r == 3) ? v : fmaxf(v - vf, 0.f);
    float c = num / rs[i2];
    size_t o = ((size_t)z * 256 + g0 + i2) * 256 + h0 + j2;
    chi[o] = (_Float16)c;
  }
}

// ---------------------------------------------------------------------------
// Final conv: fp16 GEMM, BK=64 twin subtiles, 3-buffer 2-ahead counted-vmcnt
// (6 loads/tile -> VM_BAR(6)). f32 out + bias.
__global__ __launch_bounds__(256) void k_mfma_nt1f(const _Float16* __restrict__ Ahi,
                                                   const _Float16* __restrict__ Bhi,
                                                   float* __restrict__ C,
                                                   const float* __restrict__ bias,
                                                   int M, int N, int K,
                                                   size_t Bbs, size_t Cbs) {
  __shared__ __align__(16) _Float16 Ash[3][2][128][32];
  __shared__ __align__(16) _Float16 Bsh[3][2][64][32];
  int tid = threadIdx.x;
  int z = blockIdx.z;
  const _Float16* Bh = Bhi + (size_t)z * Bbs;
  float* Cz = C + (size_t)z * Cbs;
  int bm = blockIdx.y * 128, bn = blockIdx.x * 64;
  int w = tid >> 6, lane = tid & 63;
  int wr = w >> 1, wc = w & 1;
  int l15 = lane & 15, l4 = lane >> 4;
  int rsub = lane >> 2;
  int qk = (lane & 3) * 8;
  int ar = w * 16 + rsub;
  int ar2 = ar + 64;
  f32x4 acc[4][2];
#pragma unroll
  for (int m = 0; m < 4; ++m)
#pragma unroll
    for (int n = 0; n < 2; ++n) acc[m][n] = (f32x4){0.f, 0.f, 0.f, 0.f};
  auto STG = [&](int bi, int k0) {
#pragma unroll
    for (int ks = 0; ks < 2; ++ks) {
      int kk = k0 + ks * 32;
      gll16(Ahi + (size_t)(bm + ar) * K + kk + qk,  &Ash[bi][ks][w * 16][0]);
      gll16(Ahi + (size_t)(bm + ar2) * K + kk + qk, &Ash[bi][ks][w * 16 + 64][0]);
      gll16(Bh + (size_t)(bn + ar) * K + kk + qk,   &Bsh[bi][ks][w * 16][0]);
    }
  };
  int nt = K >> 6;                  // 16
  STG(0, 0);
  STG(1, 64);
  for (int t = 0; t < nt; ++t) {
    if (t + 1 < nt) VM_BAR(6); else VM_BAR(0);
    if (t + 2 < nt) STG((t + 2) % 3, (t + 2) << 6);
    int cur = t % 3;
#pragma unroll
    for (int ks = 0; ks < 2; ++ks) {
      half8 afh[4], bfh[2];
#pragma unroll
      for (int m = 0; m < 4; ++m)
        afh[m] = *(const half8*)&Ash[cur][ks][wr * 64 + m * 16 + l15][l4 * 8];
#pragma unroll
      for (int n = 0; n < 2; ++n)
        bfh[n] = *(const half8*)&Bsh[cur][ks][wc * 32 + n * 16 + l15][l4 * 8];
#pragma unroll
      for (int m = 0; m < 4; ++m)
#pragma unroll
        for (int n = 0; n < 2; ++n)
          acc[m][n] = __builtin_amdgcn_mfma_f32_16x16x32_f16(afh[m], bfh[n], acc[m][n], 0, 0, 0);
    }
  }
#pragma unroll
  for (int m = 0; m < 4; ++m)
#pragma unroll
    for (int n = 0; n < 2; ++n)
#pragma unroll
      for (int rr = 0; rr < 4; ++rr) {
        int row = bm + wr * 64 + m * 16 + l4 * 4 + rr;
        int col = bn + wc * 32 + n * 16 + l15;
        float v = acc[m][n][rr];
        if (bias) v += bias[row];
        Cz[(size_t)row * N + col] = v;
      }
}

// ---------------------------------------------------------------------------
// dense1/dense2: fp16 GEMM, 64x64 tile, BK=64 twin subtiles, fp16 out.
// 3-buffer, 2-ahead prefetch with counted vmcnt (4 loads/tile -> VM_BAR(4)).
__global__ __launch_bounds__(256) void k_mfma_nt1f_64(const _Float16* __restrict__ Ahi,
                                                      const _Float16* __restrict__ Bhi,
                                                      _Float16* __restrict__ C,
                                                      int M, int N, int K) {
  __shared__ __align__(16) _Float16 Ash[3][2][64][32];
  __shared__ __align__(16) _Float16 Bsh[3][2][64][32];
  int tid = threadIdx.x;
  int bm = blockIdx.y * 64, bn = blockIdx.x * 64;
  int w = tid >> 6, lane = tid & 63;
  int wr = w >> 1, wc = w & 1;
  int l15 = lane & 15, l4 = lane >> 4;
  int rsub = lane >> 2;
  int qk = (lane & 3) * 8;
  int ar = w * 16 + rsub;
  f32x4 acc[2][2];
#pragma unroll
  for (int m = 0; m < 2; ++m)
#pragma unroll
    for (int n = 0; n < 2; ++n) acc[m][n] = (f32x4){0.f, 0.f, 0.f, 0.f};
  auto STG = [&](int bi, int k0) {
#pragma unroll
    for (int ks = 0; ks < 2; ++ks) {
      int kk = k0 + ks * 32;
      gll16(Ahi + (size_t)(bm + ar) * K + kk + qk, &Ash[bi][ks][w * 16][0]);
      gll16(Bhi + (size_t)(bn + ar) * K + kk + qk, &Bsh[bi][ks][w * 16][0]);
    }
  };
  int nt = K >> 6;                  // 8
  STG(0, 0);
  STG(1, 64);
  for (int t = 0; t < nt; ++t) {
    if (t + 1 < nt) VM_BAR(4); else VM_BAR(0);
    if (t + 2 < nt) STG((t + 2) % 3, (t + 2) << 6);
    int cur = t % 3;
#pragma unroll
    for (int ks = 0; ks < 2; ++ks) {
      half8 afh[2], bfh[2];
#pragma unroll
      for (int m = 0; m < 2; ++m)
        afh[m] = *(const half8*)&Ash[cur][ks][wr * 32 + m * 16 + l15][l4 * 8];
#pragma unroll
      for (int n = 0; n < 2; ++n)
        bfh[n] = *(const half8*)&Bsh[cur][ks][wc * 32 + n * 16 + l15][l4 * 8];
#pragma unroll
      for (int m = 0; m < 2; ++m)
#pragma unroll
        for (int n = 0; n < 2; ++n)
          acc[m][n] = __builtin_amdgcn_mfma_f32_16x16x32_f16(afh[m], bfh[n], acc[m][n], 0, 0, 0);
    }
  }
#pragma unroll
  for (int m = 0; m < 2; ++m)
#pragma unroll
    for (int n = 0; n < 2; ++n)
#pragma unroll
      for (int rr = 0; rr < 4; ++rr) {
        int row = bm + wr * 32 + m * 16 + l4 * 4 + rr;
        int col = bn + wc * 32 + n * 16 + l15;
        C[(size_t)row * N + col] = (_Float16)acc[m][n][rr];
      }
}

// ---------------------------------------------------------------------------
// 128x128-tile graph conv: plain fp16 GEMM, BK=32 double-buffer (32 KB LDS ->
// 5 blocks/CU; all 576 blocks co-resident), fp16 out.
__global__ __launch_bounds__(256) void k_mfma_nt1f_128(const _Float16* __restrict__ Ahi,
                                                       const _Float16* __restrict__ Bhi,
                                                       _Float16* __restrict__ C,
                                                       int M, int N, int K) {
  __shared__ __align__(16) _Float16 Ash[2][128][32];
  __shared__ __align__(16) _Float16 Bsh[2][128][32];
  int tid = threadIdx.x;
  int bm = blockIdx.y * 128, bn = blockIdx.x * 128;
  int w = tid >> 6, lane = tid & 63;
  int wr = w >> 1, wc = w & 1;
  int l15 = lane & 15, l4 = lane >> 4;
  int rsub = lane >> 2;
  int qk = (lane & 3) * 8;
  int ar = w * 16 + rsub;
  int ar2 = ar + 64;
  f32x4 acc[4][4];
#pragma unroll
  for (int m = 0; m < 4; ++m)
#pragma unroll
    for (int n = 0; n < 4; ++n) acc[m][n] = (f32x4){0.f, 0.f, 0.f, 0.f};
  auto STG = [&](int bi, int k0) {
    gll16(Ahi + (size_t)(bm + ar) * K + k0 + qk,  &Ash[bi][w * 16][0]);
    gll16(Ahi + (size_t)(bm + ar2) * K + k0 + qk, &Ash[bi][w * 16 + 64][0]);
    gll16(Bhi + (size_t)(bn + ar) * K + k0 + qk,  &Bsh[bi][w * 16][0]);
    gll16(Bhi + (size_t)(bn + ar2) * K + k0 + qk, &Bsh[bi][w * 16 + 64][0]);
  };
  int nt = K >> 5;
  STG(0, 0);
  int cur = 0;
  for (int t = 0; t < nt; ++t, cur ^= 1) {
    __syncthreads();
    if (t + 1 < nt) STG(cur ^ 1, (t + 1) << 5);
    half8 afh[4], bfh[4];
#pragma unroll
    for (int m = 0; m < 4; ++m)
      afh[m] = *(const half8*)&Ash[cur][wr * 64 + m * 16 + l15][l4 * 8];
#pragma unroll
    for (int n = 0; n < 4; ++n)
      bfh[n] = *(const half8*)&Bsh[cur][wc * 64 + n * 16 + l15][l4 * 8];
#pragma unroll
    for (int m = 0; m < 4; ++m)
#pragma unroll
      for (int n = 0; n < 4; ++n)
        acc[m][n] = __builtin_amdgcn_mfma_f32_16x16x32_f16(afh[m], bfh[n], acc[m][n], 0, 0, 0);
  }
#pragma unroll
  for (int m = 0; m < 4; ++m)
#pragma unroll
    for (int n = 0; n < 4; ++n)
#pragma unroll
      for (int rr = 0; rr < 4; ++rr) {
        int row = bm + wr * 64 + m * 16 + l4 * 4 + rr;
        int col = bn + wc * 64 + n * 16 + l15;
        C[(size_t)row * N + col] = (_Float16)acc[m][n][rr];
      }
}

// ---------------------------------------------------------------------------
// Transpose e (fp16) -> eT (fp16). Pure layout shuttle.
__global__ __launch_bounds__(256) void k_eT_split(const _Float16* __restrict__ e,
                                                  _Float16* __restrict__ eth) {
  __shared__ _Float16 tl[64][72];
  int t = threadIdx.x;
  int z = blockIdx.z;          // b*9+r
  int b = z / 9, r = z % 9;
  int h0 = blockIdx.y * 64, c0 = blockIdx.x * 64;
  const _Float16* ez = e + (size_t)b * 1179648 + (size_t)r * 131072;
  for (int k = t; k < 4096; k += 256) {
    int i = k >> 6, j = k & 63;
    tl[i][j] = ez[(size_t)(h0 + i) * 512 + c0 + j];
  }
  __syncthreads();
  for (int k = t; k < 4096; k += 256) {
    int i = k >> 6, j = k & 63;          // i: c-local, j: h-local
    size_t o = ((size_t)z * 512 + c0 + i) * 256 + h0 + j;
    eth[o] = tl[j][i];
  }
}

// ---------------------------------------------------------------------------
// h2[b,g,c] = sum_r sum_h coef[b,r,g,h] * eT[b,r,c,h] — fp16 GEMM, 64x64
// tile, BK=64 twin subtiles, 36 steps, 3-buffer 2-ahead counted-vmcnt.
__global__ __launch_bounds__(256) void k_einsum_mfma(const _Float16* __restrict__ Ahi,
                                                     const _Float16* __restrict__ Bhi,
                                                     _Float16* __restrict__ h2) {
  __shared__ __align__(16) _Float16 Ash[3][2][64][32];
  __shared__ __align__(16) _Float16 Bsh[3][2][64][32];
  int tid = threadIdx.x;
  int b = blockIdx.z;
  int bm = blockIdx.y * 64, bn = blockIdx.x * 64;
  int w = tid >> 6, lane = tid & 63;
  int wr = w >> 1, wc = w & 1;
  int l15 = lane & 15, l4 = lane >> 4;
  int rsub = lane >> 2;
  int qk = (lane & 3) * 8;
  int ar = w * 16 + rsub;
  f32x4 acc[2][2];
#pragma unroll
  for (int m = 0; m < 2; ++m)
#pragma unroll
    for (int n = 0; n < 2; ++n) acc[m][n] = (f32x4){0.f, 0.f, 0.f, 0.f};
  auto STG = [&](int bi, int kk) {
    int r = kk >> 2, k0 = (kk & 3) << 6;
    const _Float16* Ah = Ahi + ((size_t)b * 9 + r) * 65536 + (size_t)(bm + ar) * 256 + k0 + qk;
    const _Float16* Bh = Bhi + ((size_t)b * 9 + r) * 131072 + (size_t)(bn + ar) * 256 + k0 + qk;
#pragma unroll
    for (int ks = 0; ks < 2; ++ks) {
      gll16(Ah + ks * 32, &Ash[bi][ks][w * 16][0]);
      gll16(Bh + ks * 32, &Bsh[bi][ks][w * 16][0]);
    }
  };
  STG(0, 0);
  STG(1, 1);
  for (int kk = 0; kk < 36; ++kk) {
    if (kk + 1 < 36) VM_BAR(4); else VM_BAR(0);
    if (kk + 2 < 36) STG((kk + 2) % 3, kk + 2);
    int cur = kk % 3;
#pragma unroll
    for (int ks = 0; ks < 2; ++ks) {
      half8 afh[2], bfh[2];
#pragma unroll
      for (int m = 0; m < 2; ++m)
        afh[m] = *(const half8*)&Ash[cur][ks][wr * 32 + m * 16 + l15][l4 * 8];
#pragma unroll
      for (int n = 0; n < 2; ++n)
        bfh[n] = *(const half8*)&Bsh[cur][ks][wc * 32 + n * 16 + l15][l4 * 8];
#pragma unroll
      for (int m = 0; m < 2; ++m)
#pragma unroll
        for (int n = 0; n < 2; ++n)
          acc[m][n] = __builtin_amdgcn_mfma_f32_16x16x32_f16(afh[m], bfh[n], acc[m][n], 0, 0, 0);
    }
  }
#pragma unroll
  for (int m = 0; m < 2; ++m)
#pragma unroll
    for (int n = 0; n < 2; ++n)
#pragma unroll
      for (int rr = 0; rr < 4; ++rr) {
        int row = bm + wr * 32 + m * 16 + l4 * 4 + rr;
        int col = bn + wc * 32 + n * 16 + l15;
        h2[(size_t)b * 131072 + (size_t)row * 512 + col] = (_Float16)acc[m][n][rr];
      }
}

// ---------------------------------------------------------------------------
// Fused BatchNorm1d over fp16 h: wave-shfl f64 stats (2 barriers) +
// apply(+residual) + relu + fp16 out. Residual x stays f32.
__global__ __launch_bounds__(256) void k_bn_fused(const _Float16* __restrict__ h,
                                                  const float* __restrict__ gamma,
                                                  const float* __restrict__ beta,
                                                  float* __restrict__ x,
                                                  _Float16* __restrict__ ohi,
                                                  int res) {
  __shared__ double ls[4], lq[4];
  __shared__ float bc[2];
  int g = blockIdx.x;
  int tid = threadIdx.x;
  int w = tid >> 6, lane = tid & 63;
  float v[16];
  double s = 0.0, q = 0.0;
#pragma unroll
  for (int i = 0; i < 16; ++i) {
    int idx = i * 256 + tid;
    int bb = idx >> 9, c = idx & 511;
    float f = (float)h[((size_t)(bb * 256 + g) << 9) + c];
    v[i] = f;
    double d = (double)f;
    s += d; q += d * d;
  }
#pragma unroll
  for (int off = 32; off; off >>= 1) {
    s += __shfl_down(s, off, 64);
    q += __shfl_down(q, off, 64);
  }
  if (lane == 0) { ls[w] = s; lq[w] = q; }
  __syncthreads();
  if (tid == 0) {
    double st = ls[0] + ls[1] + ls[2] + ls[3];
    double qt = lq[0] + lq[1] + lq[2] + lq[3];
    double mean = st * (1.0 / 4096.0);
    double var = qt * (1.0 / 4096.0) - mean * mean;
    if (var < 0.0) var = 0.0;
    float rstd = (float)rsqrt(var + 1e-5);
    float a = gamma[g] * rstd;
    bc[0] = a;
    bc[1] = beta[g] - (float)mean * a;
  }
  __syncthreads();
  float a = bc[0], b2 = bc[1];
#pragma unroll
  for (int i = 0; i < 16; ++i) {
    int idx = i * 256 + tid;
    int bb = idx >> 9, c = idx & 511;
    size_t o = ((size_t)(bb * 256 + g) << 9) + c;
    float y = fmaf(v[i], a, b2);
    if (res) y += x[o];
    y = fmaxf(y, 0.f);
    if (res) x[o] = y;
    ohi[o] = (_Float16)y;
  }
}

// ---------------------------------------------------------------------------
// Build xcatT[b][p][c] fp16. z=0: unpool scramble of x (c<512);
// z=1: inp^T (c>=512).
__global__ __launch_bounds__(256) void k_xcatT(const float* __restrict__ x,
                                               const int* __restrict__ cntI,
                                               const int* __restrict__ gl,
                                               const float* __restrict__ inp,
                                               _Float16* __restrict__ xch) {
  __shared__ float tl[64][65];
  __shared__ int lab[1024];
  __shared__ float ic[256];
  int t = threadIdx.x;
  int b = blockIdx.y, p0 = blockIdx.x * 64;
  if (blockIdx.z == 0) {
    for (int k = t; k < 1024; k += 256) lab[k] = gl[b * 1024 + k];
    if (t < 256) ic[t] = 1.0f / ((float)cntI[b * 256 + t] + 1e-7f);
    __syncthreads();
    for (int pp = 0; pp < 64; ++pp) {
      int p = p0 + pp;
      int p9 = p >> 9, c2 = p & 511;
      const float* xb = x + (size_t)b * 131072 + c2;
      size_t obase = ((size_t)b * 1024 + p) * 1024;
#pragma unroll
      for (int ch = 0; ch < 512; ch += 256) {
        int c = ch + t;
        int g = lab[2 * c + p9];
        xch[obase + c] = (_Float16)(xb[(size_t)g * 512] * ic[g]);
      }
    }
  } else {
    for (int ct = 0; ct < 512; ct += 64) {
      __syncthreads();
      for (int k = t; k < 4096; k += 256) {
        int i = k >> 6, j = k & 63;
        tl[i][j] = inp[(size_t)b * 524288 + (size_t)(ct + i) * 1024 + p0 + j];
      }
      __syncthreads();
      for (int k = t; k < 4096; k += 256) {
        int i = k >> 6, j = k & 63;
        size_t o = ((size_t)b * 1024 + p0 + i) * 1024 + 512 + ct + j;
        xch[o] = (_Float16)tl[j][i];
      }
    }
  }
}

// ---------------------------------------------------------------------------
extern "C" void kernel_launch(void* const* d_in, const int* in_sizes, int n_in,
                              void* d_out, int out_size, void* d_ws, size_t ws_size,
                              hipStream_t stream) {
  const float* inp   = (const float*)d_in[0];
  const int*   gl    = (const int*)d_in[1];
  const float* adj   = (const float*)d_in[2];
  const float* w1    = (const float*)d_in[3];
  const float* wg    = (const float*)d_in[4];
  const float* w2    = (const float*)d_in[5];
  const float* bng   = (const float*)d_in[6];
  const float* bnb   = (const float*)d_in[7];
  const float* convw = (const float*)d_in[8];
  const float* convb = (const float*)d_in[9];
  float* out = (float*)d_out;
  float* ws = (float*)d_ws;

  _Float16* wgchi = (_Float16*)(ws + OFF_WGCH);
  _Float16* coefhi = (_Float16*)(ws + OFF_COEFH);
  float* rowsum = ws + OFF_COEF;
  float* x     = ws + OFF_X;
  int*   cntI  = (int*)(ws + OFF_CNTI);
  int*   lists = (int*)(ws + OFF_LISTS);
  int*   csrO  = (int*)(ws + OFF_CSRO);
  unsigned short* csrV = (unsigned short*)(ws + OFF_CSRV);
  _Float16* w1hi = (_Float16*)(ws + OFF_W1H);
  _Float16* w2hi = (_Float16*)(ws + OFF_W2H);
  _Float16* cwhi = (_Float16*)(ws + OFF_CWH);
  _Float16* xhi  = (_Float16*)(ws + OFF_XH);
  _Float16* hhi  = (_Float16*)(ws + OFF_HH);
  _Float16* e_h  = (_Float16*)(ws + OFF_BIG);                 // 9437184 halfs
  _Float16* eth  = (_Float16*)(ws + OFF_BIG + 4718592);       // 9437184 halfs
  _Float16* xch  = (_Float16*)(ws + OFF_BIG);                 // aliases e_h (loop done)
  float* gaT = ws + OFF_GA;
  _Float16* h1h = (_Float16*)(ws + OFF_H1);
  _Float16* h2h = (_Float16*)(ws + OFF_H2);

  hipMemsetAsync(cntI, 0, 2048 * 4, stream);

  k_lists<<<32, 256, 0, stream>>>(gl, cntI, lists);
  k_csr<<<1, 256, 0, stream>>>(cntI, lists, csrO, csrV);
  // Merged front-end: t2ga + pool first (latency-bound), then weight prep
  // (BW-bound) streams underneath.
  k_front<<<17664, 256, 0, stream>>>(wg, w1, w2, convw, wgchi, w1hi, w2hi, cwhi,
                                     adj, cntI, lists, gaT,
                                     inp, csrO, csrV, x, xhi);
  k_gasum<<<72, 256, 0, stream>>>(gaT, rowsum);
  k_coef_t<<<dim3(16, 72), 256, 0, stream>>>(gaT, rowsum, coefhi);

  for (int i = 0; i < 3; ++i) {
    // dense1: h1 = x @ w1^T  (fp16, 64x64, BK=64, 2-ahead counted-vmcnt)
    k_mfma_nt1f_64<<<dim3(8, 32), 256, 0, stream>>>(xhi, w1hi + (size_t)i * 262144,
        h1h, 2048, 512, 512);
    k_bn_fused<<<256, 256, 0, stream>>>(h1h, bng + (i * 3 + 0) * 256, bnb + (i * 3 + 0) * 256,
        nullptr, hhi, 0);
    // graph conv: e = h @ wgc^T  (fp16, BK=32 double-buffer, 5 blocks/CU)
    k_mfma_nt1f_128<<<dim3(36, 16), 256, 0, stream>>>(hhi, wgchi + (size_t)i * 2359296,
        e_h, 2048, 4608, 512);
    // coef einsum via MFMA (fp16, 64x64, BK=64, 2-ahead counted-vmcnt)
    k_eT_split<<<dim3(8, 4, 72), 256, 0, stream>>>(e_h, eth);
    k_einsum_mfma<<<dim3(8, 4, 8), 256, 0, stream>>>(coefhi, eth, h2h);
    k_bn_fused<<<256, 256, 0, stream>>>(h2h, bng + (i * 3 + 1) * 256, bnb + (i * 3 + 1) * 256,
        nullptr, hhi, 0);
    // dense2: h1 = h @ w2^T
    k_mfma_nt1f_64<<<dim3(8, 32), 256, 0, stream>>>(hhi, w2hi + (size_t)i * 262144,
        h1h, 2048, 512, 512);
    k_bn_fused<<<256, 256, 0, stream>>>(h1h, bng + (i * 3 + 2) * 256, bnb + (i * 3 + 2) * 256,
        x, xhi, 1);
  }

  k_xcatT<<<dim3(16, 8, 2), 256, 0, stream>>>(x, cntI, gl, inp, xch);
  // out[b] = convw @ xcatT[b]^T + bias  (fp16, BK=64, counted-vmcnt, f32 out)
  k_mfma_nt1f<<<dim3(16, 4, 8), 256, 0, stream>>>(cwhi, xch, out, convb,
      512, 1024, 1024, 1048576, 524288);
}

// Round 23
// 429.899 us; speedup vs baseline: 1.0290x; 1.0290x over previous
//
#include <hip/hip_runtime.h>
#include <math.h>

// Problem constants: B=8, C=512, H=W=32, N=1024, G=256, R=9
using half8 = __attribute__((ext_vector_type(8))) _Float16;
using half4 = __attribute__((ext_vector_type(4))) _Float16;
using f32x4 = __attribute__((ext_vector_type(4))) float;

// Workspace layout (f32 slots)
static constexpr size_t OFF_WGCH  = 0;           // 3*4608*512 halfs
static constexpr size_t OFF_COEF  = 7077888;     // rowsum (18432 f32)
static constexpr size_t OFF_COEFH = 11796480;    // 4718592 halfs
static constexpr size_t OFF_X     = 16515072;    // 1048576 f32
static constexpr size_t OFF_CNTI  = 17565696;    // 2048 int
static constexpr size_t OFF_LISTS = 17567744;    // 98304 int
static constexpr size_t OFF_CSRO  = 17666048;    // 2049 int (pad to 2304)
static constexpr size_t OFF_CSRV  = 17668352;    // 8192 u16
static constexpr size_t OFF_W1H   = 17672960;    // 3*512*512 halfs
static constexpr size_t OFF_W2H   = 18459392;
static constexpr size_t OFF_CWH   = 19245824;    // 512*1024 halfs
static constexpr size_t OFF_XH    = 19770112;    // 2048*512 halfs
static constexpr size_t OFF_HH    = 20818688;
static constexpr size_t OFF_BIG   = 21867264;    // 18874368 f32 region
static constexpr size_t OFF_GA    = 40741632;    // 4718592 f32 (gaT); h1/h2 alias
static constexpr size_t OFF_H1    = OFF_GA;      // 1048576 halfs
static constexpr size_t OFF_H2    = OFF_GA + 1048576;

// Direct global->LDS DMA, 16 B per lane. LDS dest = wave-uniform base + lane*16.
__device__ inline void gll16(const void* g, void* l) {
  __builtin_amdgcn_global_load_lds(
      (__attribute__((address_space(1))) void*)(size_t)g,
      (__attribute__((address_space(3))) void*)(size_t)l, 16, 0, 0);
}

// Counted-vmcnt barrier.
#define VM_BAR(N) asm volatile("s_waitcnt vmcnt(" #N ")\ns_barrier" ::: "memory")

// ---------------------------------------------------------------------------
__global__ __launch_bounds__(256) void k_lists(const int* __restrict__ gl,
                                               int* __restrict__ cntI,
                                               int* __restrict__ lists) {
  int idx = blockIdx.x * 256 + threadIdx.x;  // 8192
  int b = idx >> 10, n = idx & 1023;
  int h = gl[idx];
  int pos = atomicAdd(&cntI[b * 256 + h], 1);
  if (pos < 48) lists[(b * 256 + h) * 48 + pos] = n;
}

// Build CSR: csr_off[2049] (int), csr_val (u16 n-indices grouped by bg)
__global__ __launch_bounds__(256) void k_csr(const int* __restrict__ cntI,
                                             const int* __restrict__ lists,
                                             int* __restrict__ csr_off,
                                             unsigned short* __restrict__ csr_val) {
  __shared__ int wsum[256];
  __shared__ int tot[257];
  int t = threadIdx.x;
  int base = t * 8;
  int loc[8]; int s = 0;
#pragma unroll
  for (int i = 0; i < 8; ++i) {
    int c = cntI[base + i]; if (c > 48) c = 48;
    loc[i] = s; s += c;
  }
  wsum[t] = s;
  __syncthreads();
  if (t == 0) {
    int a = 0;
    for (int i = 0; i < 256; ++i) { tot[i] = a; a += wsum[i]; }
    tot[256] = a;
  }
  __syncthreads();
  int off0 = tot[t];
#pragma unroll
  for (int i = 0; i < 8; ++i) {
    int bg = base + i;
    int o = off0 + loc[i];
    csr_off[bg] = o;
    int c = cntI[bg]; if (c > 48) c = 48;
    for (int j = 0; j < c; ++j)
      csr_val[o + j] = (unsigned short)(lists[bg * 48 + j] & 1023);
  }
  if (t == 0) csr_off[2048] = tot[256];
}

// ---------------------------------------------------------------------------
// Merged front-end, PERSISTENT-BLOCK form: 2560 blocks total.
//   blocks [0,2048):    t2ga gather (gaT), then grid-stride prep
//   blocks [2048,2560): pool via CSR (x, xh), then grid-stride prep
// The prep workload (wg collapse 1769472 float4-units + 2097152 cast units)
// is distributed by a grid-stride loop over all 2560 blocks after each
// finishes its gather unit — eliminating 15104 one-shot block dispatches
// and keeping deep load pipelines alive across units.
__global__ __launch_bounds__(256) void k_front(const float* __restrict__ wg,
                                               const float* __restrict__ w1,
                                               const float* __restrict__ w2,
                                               const float* __restrict__ cw,
                                               _Float16* __restrict__ wgh,
                                               _Float16* __restrict__ w1h,
                                               _Float16* __restrict__ w2h,
                                               _Float16* __restrict__ cwh,
                                               const float* __restrict__ adj,
                                               const int* __restrict__ cntI,
                                               const int* __restrict__ lists,
                                               float* __restrict__ gaT,
                                               const float* __restrict__ inp,
                                               const int* __restrict__ csr_off,
                                               const unsigned short* __restrict__ csr_val,
                                               float* __restrict__ x,
                                               _Float16* __restrict__ xh) {
  __shared__ __align__(16) char smem[37120];
  int bid = blockIdx.x;
  int t = threadIdx.x;
  if (bid < 2048) {
    // ---- t2ga: gaT[b,r,h,g] = sum_{m in g} sum_{n in h} adj[r,n,m] ----
    float (*ul)[1024] = (float(*)[1024])smem;          // 9*1024*4 = 36864 B
    int* lsh = (int*)(smem + 36864);                   // 48*4 = 192 B
    int b = bid >> 8, h = bid & 255;
    int cnt = cntI[b * 256 + h]; if (cnt > 48) cnt = 48;
    if (t < cnt) lsh[t] = lists[(b * 256 + h) * 48 + t];
    __syncthreads();
    float u[9][4];
#pragma unroll
    for (int r = 0; r < 9; ++r)
#pragma unroll
      for (int j = 0; j < 4; ++j) u[r][j] = 0.f;
    for (int i = 0; i < cnt; ++i) {
      const float* base = adj + ((size_t)lsh[i] << 10) + t;
#pragma unroll
      for (int r = 0; r < 9; ++r) {
        const float* p = base + (size_t)r * 1048576;
        u[r][0] += p[0];
        u[r][1] += p[256];
        u[r][2] += p[512];
        u[r][3] += p[768];
      }
    }
#pragma unroll
    for (int r = 0; r < 9; ++r)
#pragma unroll
      for (int j = 0; j < 4; ++j) ul[r][j * 256 + t] = u[r][j];
    __syncthreads();
    int g = t;
    int cg = cntI[b * 256 + g]; if (cg > 48) cg = 48;
    const int* lg = lists + (b * 256 + g) * 48;
    float s[9];
#pragma unroll
    for (int r = 0; r < 9; ++r) s[r] = 0.f;
    for (int i = 0; i < cg; ++i) {
      int m = lg[i];
#pragma unroll
      for (int r = 0; r < 9; ++r) s[r] += ul[r][m];
    }
#pragma unroll
    for (int r = 0; r < 9; ++r)
      gaT[(((size_t)(b * 9 + r)) * 256 + h) * 256 + g] = s[r];
  } else {
    // ---- pool via CSR; emits x (f32) and fp16 cast ----
    float (*rows)[1032] = (float(*)[1032])smem;        // 8*1032*4 = 33024 B
    int* offs = (int*)(smem + 33024);                  // 257*4 = 1028 B
    unsigned short* vals = (unsigned short*)(smem + 33024 + 1028);  // 2048 B
    int blk = bid - 2048;
    int b = blk >> 6, cch = blk & 63;
    const float4* src = (const float4*)(inp + (size_t)b * 524288 + (size_t)cch * 8 * 1024);
    for (int k = t; k < 2048; k += 256) {
      float4 v = src[k];
      int c = k >> 8;
      int m = (k & 255) << 2;
      *(float4*)&rows[c][m] = v;
    }
    for (int k = t; k < 257; k += 256) offs[k] = csr_off[b * 256 + k];
    __syncthreads();
    int vbase = offs[0];
    int nv = offs[256] - vbase;
    for (int k = t; k < nv; k += 256) vals[k] = csr_val[vbase + k];
    __syncthreads();
    int g = t;
    int o0 = offs[g] - vbase, o1 = offs[g + 1] - vbase;
    float s[8] = {0.f, 0.f, 0.f, 0.f, 0.f, 0.f, 0.f, 0.f};
    for (int i = o0; i < o1; ++i) {
      int n = vals[i];
#pragma unroll
      for (int c = 0; c < 8; ++c) s[c] += rows[c][n];
    }
    const float sc = 1.0f / (1.0f + 1e-7f);
    size_t xbase = ((size_t)b * 256 + g) * 512 + cch * 8;
#pragma unroll
    for (int c = 0; c < 8; ++c) {
      float v = s[c] * sc;
      x[xbase + c] = v;
      xh[xbase + c] = (_Float16)v;
    }
  }
  // ---- grid-stride prep phase (all 2560 blocks) ----
  const size_t NSTRIDE = (size_t)2560 * 256;
  for (size_t u = (size_t)bid * 256 + t; u < 3866624u; u += NSTRIDE) {
    if (u < 1769472u) {
      // wg collapse (float4/unit, fp16 out)
      size_t i = u / (4608u * 128u);
      size_t rem = u % (4608u * 128u);
      size_t j = rem / 128u, c4 = rem % 128u;
      const float* p = wg + i * 21233664ull + j * 4608ull + c4 * 4;
      float4 s = {0.f, 0.f, 0.f, 0.f};
#pragma unroll
      for (int r = 0; r < 9; ++r) {
        float4 v = *(const float4*)(p + r * 512);
        s.x += v.x; s.y += v.y; s.z += v.z; s.w += v.w;
      }
      half4 hv;
      hv[0] = (_Float16)s.x; hv[1] = (_Float16)s.y;
      hv[2] = (_Float16)s.z; hv[3] = (_Float16)s.w;
      *(half4*)&wgh[u * 4] = hv;
    } else {
      size_t idx = u - 1769472u;   // 2097152 cast units
      if (idx < 786432) {
        w1h[idx] = (_Float16)w1[idx];
      } else if (idx < 1572864) {
        size_t o = idx - 786432;
        w2h[o] = (_Float16)w2[o];
      } else {
        size_t o = idx - 1572864;
        cwh[o] = (_Float16)cw[o];
      }
    }
  }
}

// rowsum[z,g] = sum_h gaT[z,h,g]
__global__ __launch_bounds__(256) void k_gasum(const float* __restrict__ gaT,
                                               float* __restrict__ rowsum) {
  int z = blockIdx.x;            // 72
  int t = threadIdx.x;           // g
  const float* p = gaT + ((size_t)z * 256) * 256 + t;
  float s = 0.f;
  for (int h = 0; h < 256; ++h) s += p[(size_t)h * 256];
  rowsum[z * 256 + t] = s;
}

// coef via 64x64 LDS transpose tiles; fp16.
__global__ __launch_bounds__(256) void k_coef_t(const float* __restrict__ gaT,
                                                const float* __restrict__ rowsum,
                                                _Float16* __restrict__ chi) {
  __shared__ float tl[64][65];
  __shared__ float tlf[64][65];
  __shared__ float rs[64];
  int t = threadIdx.x;
  int z = blockIdx.y;            // b*9+r
  int b = z / 9, r = z % 9;
  int tile = blockIdx.x;         // 16
  int h0 = (tile & 3) * 64, g0 = (tile >> 2) * 64;
  size_t base  = ((size_t)z * 256 + h0) * 256 + g0;
  size_t baseF = ((size_t)((7 - b) * 9 + r) * 256 + h0) * 256 + g0;
  for (int k = t; k < 4096; k += 256) {
    int i = k >> 6, j = k & 63;
    tl[i][j]  = gaT[base  + (size_t)i * 256 + j];
    tlf[i][j] = gaT[baseF + (size_t)i * 256 + j];
  }
  if (t < 64) rs[t] = rowsum[z * 256 + g0 + t] + 1.0f;
  __syncthreads();
  for (int k = t; k < 4096; k += 256) {
    int i2 = k >> 6, j2 = k & 63;        // i2: g-local, j2: h-local
    float v = tl[j2][i2], vf = tlf[j2][i2];
    float num = (r == 3) ? v : fmaxf(v - vf, 0.f);
    float c = num / rs[i2];
    size_t o = ((size_t)z * 256 + g0 + i2) * 256 + h0 + j2;
    chi[o] = (_Float16)c;
  }
}

// ---------------------------------------------------------------------------
// Final conv: fp16 GEMM, BK=64 twin subtiles, 3-buffer 2-ahead counted-vmcnt
// (6 loads/tile -> VM_BAR(6)). f32 out + bias.
__global__ __launch_bounds__(256) void k_mfma_nt1f(const _Float16* __restrict__ Ahi,
                                                   const _Float16* __restrict__ Bhi,
                                                   float* __restrict__ C,
                                                   const float* __restrict__ bias,
                                                   int M, int N, int K,
                                                   size_t Bbs, size_t Cbs) {
  __shared__ __align__(16) _Float16 Ash[3][2][128][32];
  __shared__ __align__(16) _Float16 Bsh[3][2][64][32];
  int tid = threadIdx.x;
  int z = blockIdx.z;
  const _Float16* Bh = Bhi + (size_t)z * Bbs;
  float* Cz = C + (size_t)z * Cbs;
  int bm = blockIdx.y * 128, bn = blockIdx.x * 64;
  int w = tid >> 6, lane = tid & 63;
  int wr = w >> 1, wc = w & 1;
  int l15 = lane & 15, l4 = lane >> 4;
  int rsub = lane >> 2;
  int qk = (lane & 3) * 8;
  int ar = w * 16 + rsub;
  int ar2 = ar + 64;
  f32x4 acc[4][2];
#pragma unroll
  for (int m = 0; m < 4; ++m)
#pragma unroll
    for (int n = 0; n < 2; ++n) acc[m][n] = (f32x4){0.f, 0.f, 0.f, 0.f};
  auto STG = [&](int bi, int k0) {
#pragma unroll
    for (int ks = 0; ks < 2; ++ks) {
      int kk = k0 + ks * 32;
      gll16(Ahi + (size_t)(bm + ar) * K + kk + qk,  &Ash[bi][ks][w * 16][0]);
      gll16(Ahi + (size_t)(bm + ar2) * K + kk + qk, &Ash[bi][ks][w * 16 + 64][0]);
      gll16(Bh + (size_t)(bn + ar) * K + kk + qk,   &Bsh[bi][ks][w * 16][0]);
    }
  };
  int nt = K >> 6;                  // 16
  STG(0, 0);
  STG(1, 64);
  for (int t = 0; t < nt; ++t) {
    if (t + 1 < nt) VM_BAR(6); else VM_BAR(0);
    if (t + 2 < nt) STG((t + 2) % 3, (t + 2) << 6);
    int cur = t % 3;
#pragma unroll
    for (int ks = 0; ks < 2; ++ks) {
      half8 afh[4], bfh[2];
#pragma unroll
      for (int m = 0; m < 4; ++m)
        afh[m] = *(const half8*)&Ash[cur][ks][wr * 64 + m * 16 + l15][l4 * 8];
#pragma unroll
      for (int n = 0; n < 2; ++n)
        bfh[n] = *(const half8*)&Bsh[cur][ks][wc * 32 + n * 16 + l15][l4 * 8];
#pragma unroll
      for (int m = 0; m < 4; ++m)
#pragma unroll
        for (int n = 0; n < 2; ++n)
          acc[m][n] = __builtin_amdgcn_mfma_f32_16x16x32_f16(afh[m], bfh[n], acc[m][n], 0, 0, 0);
    }
  }
#pragma unroll
  for (int m = 0; m < 4; ++m)
#pragma unroll
    for (int n = 0; n < 2; ++n)
#pragma unroll
      for (int rr = 0; rr < 4; ++rr) {
        int row = bm + wr * 64 + m * 16 + l4 * 4 + rr;
        int col = bn + wc * 32 + n * 16 + l15;
        float v = acc[m][n][rr];
        if (bias) v += bias[row];
        Cz[(size_t)row * N + col] = v;
      }
}

// ---------------------------------------------------------------------------
// dense1/dense2: fp16 GEMM, 64x64 tile, BK=64 twin subtiles, fp16 out.
// 3-buffer, 2-ahead prefetch with counted vmcnt (4 loads/tile -> VM_BAR(4)).
__global__ __launch_bounds__(256) void k_mfma_nt1f_64(const _Float16* __restrict__ Ahi,
                                                      const _Float16* __restrict__ Bhi,
                                                      _Float16* __restrict__ C,
                                                      int M, int N, int K) {
  __shared__ __align__(16) _Float16 Ash[3][2][64][32];
  __shared__ __align__(16) _Float16 Bsh[3][2][64][32];
  int tid = threadIdx.x;
  int bm = blockIdx.y * 64, bn = blockIdx.x * 64;
  int w = tid >> 6, lane = tid & 63;
  int wr = w >> 1, wc = w & 1;
  int l15 = lane & 15, l4 = lane >> 4;
  int rsub = lane >> 2;
  int qk = (lane & 3) * 8;
  int ar = w * 16 + rsub;
  f32x4 acc[2][2];
#pragma unroll
  for (int m = 0; m < 2; ++m)
#pragma unroll
    for (int n = 0; n < 2; ++n) acc[m][n] = (f32x4){0.f, 0.f, 0.f, 0.f};
  auto STG = [&](int bi, int k0) {
#pragma unroll
    for (int ks = 0; ks < 2; ++ks) {
      int kk = k0 + ks * 32;
      gll16(Ahi + (size_t)(bm + ar) * K + kk + qk, &Ash[bi][ks][w * 16][0]);
      gll16(Bhi + (size_t)(bn + ar) * K + kk + qk, &Bsh[bi][ks][w * 16][0]);
    }
  };
  int nt = K >> 6;                  // 8
  STG(0, 0);
  STG(1, 64);
  for (int t = 0; t < nt; ++t) {
    if (t + 1 < nt) VM_BAR(4); else VM_BAR(0);
    if (t + 2 < nt) STG((t + 2) % 3, (t + 2) << 6);
    int cur = t % 3;
#pragma unroll
    for (int ks = 0; ks < 2; ++ks) {
      half8 afh[2], bfh[2];
#pragma unroll
      for (int m = 0; m < 2; ++m)
        afh[m] = *(const half8*)&Ash[cur][ks][wr * 32 + m * 16 + l15][l4 * 8];
#pragma unroll
      for (int n = 0; n < 2; ++n)
        bfh[n] = *(const half8*)&Bsh[cur][ks][wc * 32 + n * 16 + l15][l4 * 8];
#pragma unroll
      for (int m = 0; m < 2; ++m)
#pragma unroll
        for (int n = 0; n < 2; ++n)
          acc[m][n] = __builtin_amdgcn_mfma_f32_16x16x32_f16(afh[m], bfh[n], acc[m][n], 0, 0, 0);
    }
  }
#pragma unroll
  for (int m = 0; m < 2; ++m)
#pragma unroll
    for (int n = 0; n < 2; ++n)
#pragma unroll
      for (int rr = 0; rr < 4; ++rr) {
        int row = bm + wr * 32 + m * 16 + l4 * 4 + rr;
        int col = bn + wc * 32 + n * 16 + l15;
        C[(size_t)row * N + col] = (_Float16)acc[m][n][rr];
      }
}

// ---------------------------------------------------------------------------
// 128x128-tile graph conv: plain fp16 GEMM, BK=32 double-buffer (32 KB LDS ->
// 5 blocks/CU; all 576 blocks co-resident), fp16 out.
__global__ __launch_bounds__(256) void k_mfma_nt1f_128(const _Float16* __restrict__ Ahi,
                                                       const _Float16* __restrict__ Bhi,
                                                       _Float16* __restrict__ C,
                                                       int M, int N, int K) {
  __shared__ __align__(16) _Float16 Ash[2][128][32];
  __shared__ __align__(16) _Float16 Bsh[2][128][32];
  int tid = threadIdx.x;
  int bm = blockIdx.y * 128, bn = blockIdx.x * 128;
  int w = tid >> 6, lane = tid & 63;
  int wr = w >> 1, wc = w & 1;
  int l15 = lane & 15, l4 = lane >> 4;
  int rsub = lane >> 2;
  int qk = (lane & 3) * 8;
  int ar = w * 16 + rsub;
  int ar2 = ar + 64;
  f32x4 acc[4][4];
#pragma unroll
  for (int m = 0; m < 4; ++m)
#pragma unroll
    for (int n = 0; n < 4; ++n) acc[m][n] = (f32x4){0.f, 0.f, 0.f, 0.f};
  auto STG = [&](int bi, int k0) {
    gll16(Ahi + (size_t)(bm + ar) * K + k0 + qk,  &Ash[bi][w * 16][0]);
    gll16(Ahi + (size_t)(bm + ar2) * K + k0 + qk, &Ash[bi][w * 16 + 64][0]);
    gll16(Bhi + (size_t)(bn + ar) * K + k0 + qk,  &Bsh[bi][w * 16][0]);
    gll16(Bhi + (size_t)(bn + ar2) * K + k0 + qk, &Bsh[bi][w * 16 + 64][0]);
  };
  int nt = K >> 5;
  STG(0, 0);
  int cur = 0;
  for (int t = 0; t < nt; ++t, cur ^= 1) {
    __syncthreads();
    if (t + 1 < nt) STG(cur ^ 1, (t + 1) << 5);
    half8 afh[4], bfh[4];
#pragma unroll
    for (int m = 0; m < 4; ++m)
      afh[m] = *(const half8*)&Ash[cur][wr * 64 + m * 16 + l15][l4 * 8];
#pragma unroll
    for (int n = 0; n < 4; ++n)
      bfh[n] = *(const half8*)&Bsh[cur][wc * 64 + n * 16 + l15][l4 * 8];
#pragma unroll
    for (int m = 0; m < 4; ++m)
#pragma unroll
      for (int n = 0; n < 4; ++n)
        acc[m][n] = __builtin_amdgcn_mfma_f32_16x16x32_f16(afh[m], bfh[n], acc[m][n], 0, 0, 0);
  }
#pragma unroll
  for (int m = 0; m < 4; ++m)
#pragma unroll
    for (int n = 0; n < 4; ++n)
#pragma unroll
      for (int rr = 0; rr < 4; ++rr) {
        int row = bm + wr * 64 + m * 16 + l4 * 4 + rr;
        int col = bn + wc * 64 + n * 16 + l15;
        C[(size_t)row * N + col] = (_Float16)acc[m][n][rr];
      }
}

// ---------------------------------------------------------------------------
// Transpose e (fp16) -> eT (fp16). Pure layout shuttle.
__global__ __launch_bounds__(256) void k_eT_split(const _Float16* __restrict__ e,
                                                  _Float16* __restrict__ eth) {
  __shared__ _Float16 tl[64][72];
  int t = threadIdx.x;
  int z = blockIdx.z;          // b*9+r
  int b = z / 9, r = z % 9;
  int h0 = blockIdx.y * 64, c0 = blockIdx.x * 64;
  const _Float16* ez = e + (size_t)b * 1179648 + (size_t)r * 131072;
  for (int k = t; k < 4096; k += 256) {
    int i = k >> 6, j = k & 63;
    tl[i][j] = ez[(size_t)(h0 + i) * 512 + c0 + j];
  }
  __syncthreads();
  for (int k = t; k < 4096; k += 256) {
    int i = k >> 6, j = k & 63;          // i: c-local, j: h-local
    size_t o = ((size_t)z * 512 + c0 + i) * 256 + h0 + j;
    eth[o] = tl[j][i];
  }
}

// ---------------------------------------------------------------------------
// h2[b,g,c] = sum_r sum_h coef[b,r,g,h] * eT[b,r,c,h] — fp16 GEMM, 64x64
// tile, BK=64 twin subtiles, 36 steps, 3-buffer 2-ahead counted-vmcnt.
__global__ __launch_bounds__(256) void k_einsum_mfma(const _Float16* __restrict__ Ahi,
                                                     const _Float16* __restrict__ Bhi,
                                                     _Float16* __restrict__ h2) {
  __shared__ __align__(16) _Float16 Ash[3][2][64][32];
  __shared__ __align__(16) _Float16 Bsh[3][2][64][32];
  int tid = threadIdx.x;
  int b = blockIdx.z;
  int bm = blockIdx.y * 64, bn = blockIdx.x * 64;
  int w = tid >> 6, lane = tid & 63;
  int wr = w >> 1, wc = w & 1;
  int l15 = lane & 15, l4 = lane >> 4;
  int rsub = lane >> 2;
  int qk = (lane & 3) * 8;
  int ar = w * 16 + rsub;
  f32x4 acc[2][2];
#pragma unroll
  for (int m = 0; m < 2; ++m)
#pragma unroll
    for (int n = 0; n < 2; ++n) acc[m][n] = (f32x4){0.f, 0.f, 0.f, 0.f};
  auto STG = [&](int bi, int kk) {
    int r = kk >> 2, k0 = (kk & 3) << 6;
    const _Float16* Ah = Ahi + ((size_t)b * 9 + r) * 65536 + (size_t)(bm + ar) * 256 + k0 + qk;
    const _Float16* Bh = Bhi + ((size_t)b * 9 + r) * 131072 + (size_t)(bn + ar) * 256 + k0 + qk;
#pragma unroll
    for (int ks = 0; ks < 2; ++ks) {
      gll16(Ah + ks * 32, &Ash[bi][ks][w * 16][0]);
      gll16(Bh + ks * 32, &Bsh[bi][ks][w * 16][0]);
    }
  };
  STG(0, 0);
  STG(1, 1);
  for (int kk = 0; kk < 36; ++kk) {
    if (kk + 1 < 36) VM_BAR(4); else VM_BAR(0);
    if (kk + 2 < 36) STG((kk + 2) % 3, kk + 2);
    int cur = kk % 3;
#pragma unroll
    for (int ks = 0; ks < 2; ++ks) {
      half8 afh[2], bfh[2];
#pragma unroll
      for (int m = 0; m < 2; ++m)
        afh[m] = *(const half8*)&Ash[cur][ks][wr * 32 + m * 16 + l15][l4 * 8];
#pragma unroll
      for (int n = 0; n < 2; ++n)
        bfh[n] = *(const half8*)&Bsh[cur][ks][wc * 32 + n * 16 + l15][l4 * 8];
#pragma unroll
      for (int m = 0; m < 2; ++m)
#pragma unroll
        for (int n = 0; n < 2; ++n)
          acc[m][n] = __builtin_amdgcn_mfma_f32_16x16x32_f16(afh[m], bfh[n], acc[m][n], 0, 0, 0);
    }
  }
#pragma unroll
  for (int m = 0; m < 2; ++m)
#pragma unroll
    for (int n = 0; n < 2; ++n)
#pragma unroll
      for (int rr = 0; rr < 4; ++rr) {
        int row = bm + wr * 32 + m * 16 + l4 * 4 + rr;
        int col = bn + wc * 32 + n * 16 + l15;
        h2[(size_t)b * 131072 + (size_t)row * 512 + col] = (_Float16)acc[m][n][rr];
      }
}

// ---------------------------------------------------------------------------
// Fused BatchNorm1d over fp16 h: wave-shfl f64 stats (2 barriers) +
// apply(+residual) + relu + fp16 out. Residual x stays f32.
__global__ __launch_bounds__(256) void k_bn_fused(const _Float16* __restrict__ h,
                                                  const float* __restrict__ gamma,
                                                  const float* __restrict__ beta,
                                                  float* __restrict__ x,
                                                  _Float16* __restrict__ ohi,
                                                  int res) {
  __shared__ double ls[4], lq[4];
  __shared__ float bc[2];
  int g = blockIdx.x;
  int tid = threadIdx.x;
  int w = tid >> 6, lane = tid & 63;
  float v[16];
  double s = 0.0, q = 0.0;
#pragma unroll
  for (int i = 0; i < 16; ++i) {
    int idx = i * 256 + tid;
    int bb = idx >> 9, c = idx & 511;
    float f = (float)h[((size_t)(bb * 256 + g) << 9) + c];
    v[i] = f;
    double d = (double)f;
    s += d; q += d * d;
  }
#pragma unroll
  for (int off = 32; off; off >>= 1) {
    s += __shfl_down(s, off, 64);
    q += __shfl_down(q, off, 64);
  }
  if (lane == 0) { ls[w] = s; lq[w] = q; }
  __syncthreads();
  if (tid == 0) {
    double st = ls[0] + ls[1] + ls[2] + ls[3];
    double qt = lq[0] + lq[1] + lq[2] + lq[3];
    double mean = st * (1.0 / 4096.0);
    double var = qt * (1.0 / 4096.0) - mean * mean;
    if (var < 0.0) var = 0.0;
    float rstd = (float)rsqrt(var + 1e-5);
    float a = gamma[g] * rstd;
    bc[0] = a;
    bc[1] = beta[g] - (float)mean * a;
  }
  __syncthreads();
  float a = bc[0], b2 = bc[1];
#pragma unroll
  for (int i = 0; i < 16; ++i) {
    int idx = i * 256 + tid;
    int bb = idx >> 9, c = idx & 511;
    size_t o = ((size_t)(bb * 256 + g) << 9) + c;
    float y = fmaf(v[i], a, b2);
    if (res) y += x[o];
    y = fmaxf(y, 0.f);
    if (res) x[o] = y;
    ohi[o] = (_Float16)y;
  }
}

// ---------------------------------------------------------------------------
// Build xcatT[b][p][c] fp16. z=0: unpool scramble of x (c<512);
// z=1: inp^T (c>=512).
__global__ __launch_bounds__(256) void k_xcatT(const float* __restrict__ x,
                                               const int* __restrict__ cntI,
                                               const int* __restrict__ gl,
                                               const float* __restrict__ inp,
                                               _Float16* __restrict__ xch) {
  __shared__ float tl[64][65];
  __shared__ int lab[1024];
  __shared__ float ic[256];
  int t = threadIdx.x;
  int b = blockIdx.y, p0 = blockIdx.x * 64;
  if (blockIdx.z == 0) {
    for (int k = t; k < 1024; k += 256) lab[k] = gl[b * 1024 + k];
    if (t < 256) ic[t] = 1.0f / ((float)cntI[b * 256 + t] + 1e-7f);
    __syncthreads();
    for (int pp = 0; pp < 64; ++pp) {
      int p = p0 + pp;
      int p9 = p >> 9, c2 = p & 511;
      const float* xb = x + (size_t)b * 131072 + c2;
      size_t obase = ((size_t)b * 1024 + p) * 1024;
#pragma unroll
      for (int ch = 0; ch < 512; ch += 256) {
        int c = ch + t;
        int g = lab[2 * c + p9];
        xch[obase + c] = (_Float16)(xb[(size_t)g * 512] * ic[g]);
      }
    }
  } else {
    for (int ct = 0; ct < 512; ct += 64) {
      __syncthreads();
      for (int k = t; k < 4096; k += 256) {
        int i = k >> 6, j = k & 63;
        tl[i][j] = inp[(size_t)b * 524288 + (size_t)(ct + i) * 1024 + p0 + j];
      }
      __syncthreads();
      for (int k = t; k < 4096; k += 256) {
        int i = k >> 6, j = k & 63;
        size_t o = ((size_t)b * 1024 + p0 + i) * 1024 + 512 + ct + j;
        xch[o] = (_Float16)tl[j][i];
      }
    }
  }
}

// ---------------------------------------------------------------------------
extern "C" void kernel_launch(void* const* d_in, const int* in_sizes, int n_in,
                              void* d_out, int out_size, void* d_ws, size_t ws_size,
                              hipStream_t stream) {
  const float* inp   = (const float*)d_in[0];
  const int*   gl    = (const int*)d_in[1];
  const float* adj   = (const float*)d_in[2];
  const float* w1    = (const float*)d_in[3];
  const float* wg    = (const float*)d_in[4];
  const float* w2    = (const float*)d_in[5];
  const float* bng   = (const float*)d_in[6];
  const float* bnb   = (const float*)d_in[7];
  const float* convw = (const float*)d_in[8];
  const float* convb = (const float*)d_in[9];
  float* out = (float*)d_out;
  float* ws = (float*)d_ws;

  _Float16* wgchi = (_Float16*)(ws + OFF_WGCH);
  _Float16* coefhi = (_Float16*)(ws + OFF_COEFH);
  float* rowsum = ws + OFF_COEF;
  float* x     = ws + OFF_X;
  int*   cntI  = (int*)(ws + OFF_CNTI);
  int*   lists = (int*)(ws + OFF_LISTS);
  int*   csrO  = (int*)(ws + OFF_CSRO);
  unsigned short* csrV = (unsigned short*)(ws + OFF_CSRV);
  _Float16* w1hi = (_Float16*)(ws + OFF_W1H);
  _Float16* w2hi = (_Float16*)(ws + OFF_W2H);
  _Float16* cwhi = (_Float16*)(ws + OFF_CWH);
  _Float16* xhi  = (_Float16*)(ws + OFF_XH);
  _Float16* hhi  = (_Float16*)(ws + OFF_HH);
  _Float16* e_h  = (_Float16*)(ws + OFF_BIG);                 // 9437184 halfs
  _Float16* eth  = (_Float16*)(ws + OFF_BIG + 4718592);       // 9437184 halfs
  _Float16* xch  = (_Float16*)(ws + OFF_BIG);                 // aliases e_h (loop done)
  float* gaT = ws + OFF_GA;
  _Float16* h1h = (_Float16*)(ws + OFF_H1);
  _Float16* h2h = (_Float16*)(ws + OFF_H2);

  hipMemsetAsync(cntI, 0, 2048 * 4, stream);

  k_lists<<<32, 256, 0, stream>>>(gl, cntI, lists);
  k_csr<<<1, 256, 0, stream>>>(cntI, lists, csrO, csrV);
  // Merged front-end, persistent-block form: 2560 blocks do t2ga/pool units
  // then grid-stride the whole weight-prep workload.
  k_front<<<2560, 256, 0, stream>>>(wg, w1, w2, convw, wgchi, w1hi, w2hi, cwhi,
                                    adj, cntI, lists, gaT,
                                    inp, csrO, csrV, x, xhi);
  k_gasum<<<72, 256, 0, stream>>>(gaT, rowsum);
  k_coef_t<<<dim3(16, 72), 256, 0, stream>>>(gaT, rowsum, coefhi);

  for (int i = 0; i < 3; ++i) {
    // dense1: h1 = x @ w1^T  (fp16, 64x64, BK=64, 2-ahead counted-vmcnt)
    k_mfma_nt1f_64<<<dim3(8, 32), 256, 0, stream>>>(xhi, w1hi + (size_t)i * 262144,
        h1h, 2048, 512, 512);
    k_bn_fused<<<256, 256, 0, stream>>>(h1h, bng + (i * 3 + 0) * 256, bnb + (i * 3 + 0) * 256,
        nullptr, hhi, 0);
    // graph conv: e = h @ wgc^T  (fp16, BK=32 double-buffer, 5 blocks/CU)
    k_mfma_nt1f_128<<<dim3(36, 16), 256, 0, stream>>>(hhi, wgchi + (size_t)i * 2359296,
        e_h, 2048, 4608, 512);
    // coef einsum via MFMA (fp16, 64x64, BK=64, 2-ahead counted-vmcnt)
    k_eT_split<<<dim3(8, 4, 72), 256, 0, stream>>>(e_h, eth);
    k_einsum_mfma<<<dim3(8, 4, 8), 256, 0, stream>>>(coefhi, eth, h2h);
    k_bn_fused<<<256, 256, 0, stream>>>(h2h, bng + (i * 3 + 1) * 256, bnb + (i * 3 + 1) * 256,
        nullptr, hhi, 0);
    // dense2: h1 = h @ w2^T
    k_mfma_nt1f_64<<<dim3(8, 32), 256, 0, stream>>>(hhi, w2hi + (size_t)i * 262144,
        h1h, 2048, 512, 512);
    k_bn_fused<<<256, 256, 0, stream>>>(h1h, bng + (i * 3 + 2) * 256, bnb + (i * 3 + 2) * 256,
        x, xhi, 1);
  }

  k_xcatT<<<dim3(16, 8, 2), 256, 0, stream>>>(x, cntI, gl, inp, xch);
  // out[b] = convw @ xcatT[b]^T + bias  (fp16, BK=64, counted-vmcnt, f32 out)
  k_mfma_nt1f<<<dim3(16, 4, 8), 256, 0, stream>>>(cwhi, xch, out, convb,
      512, 1024, 1024, 1048576, 524288);
}

// Round 24
// 423.722 us; speedup vs baseline: 1.0440x; 1.0146x over previous
//
#include <hip/hip_runtime.h>
#include <math.h>

// Problem constants: B=8, C=512, H=W=32, N=1024, G=256, R=9
using half8 = __attribute__((ext_vector_type(8))) _Float16;
using half4 = __attribute__((ext_vector_type(4))) _Float16;
using f32x4 = __attribute__((ext_vector_type(4))) float;

// Workspace layout (f32 slots)
static constexpr size_t OFF_WGCH  = 0;           // 3*4608*512 halfs
static constexpr size_t OFF_COEF  = 7077888;     // rowsum (18432 f32)
static constexpr size_t OFF_COEFH = 11796480;    // 4718592 halfs
static constexpr size_t OFF_X     = 16515072;    // 1048576 f32
static constexpr size_t OFF_CNTI  = 17565696;    // 2048 int
static constexpr size_t OFF_LISTS = 17567744;    // 98304 int
static constexpr size_t OFF_CSRO  = 17666048;    // 2049 int (pad to 2304)
static constexpr size_t OFF_CSRV  = 17668352;    // 8192 u16
static constexpr size_t OFF_W1H   = 17672960;    // 3*512*512 halfs
static constexpr size_t OFF_W2H   = 18459392;
static constexpr size_t OFF_CWH   = 19245824;    // 512*1024 halfs
static constexpr size_t OFF_XH    = 19770112;    // 2048*512 halfs
static constexpr size_t OFF_HH    = 20818688;
static constexpr size_t OFF_BIG   = 21867264;    // 18874368 f32 region
static constexpr size_t OFF_GA    = 40741632;    // 4718592 f32 (gaT); h1/h2 alias
static constexpr size_t OFF_H1    = OFF_GA;      // 1048576 halfs
static constexpr size_t OFF_H2    = OFF_GA + 1048576;

// Direct global->LDS DMA, 16 B per lane. LDS dest = wave-uniform base + lane*16.
__device__ inline void gll16(const void* g, void* l) {
  __builtin_amdgcn_global_load_lds(
      (__attribute__((address_space(1))) void*)(size_t)g,
      (__attribute__((address_space(3))) void*)(size_t)l, 16, 0, 0);
}

// Counted-vmcnt barrier.
#define VM_BAR(N) asm volatile("s_waitcnt vmcnt(" #N ")\ns_barrier" ::: "memory")

// ---------------------------------------------------------------------------
__global__ __launch_bounds__(256) void k_lists(const int* __restrict__ gl,
                                               int* __restrict__ cntI,
                                               int* __restrict__ lists) {
  int idx = blockIdx.x * 256 + threadIdx.x;  // 8192
  int b = idx >> 10, n = idx & 1023;
  int h = gl[idx];
  int pos = atomicAdd(&cntI[b * 256 + h], 1);
  if (pos < 48) lists[(b * 256 + h) * 48 + pos] = n;
}

// Build CSR: csr_off[2049] (int), csr_val (u16 n-indices grouped by bg)
__global__ __launch_bounds__(256) void k_csr(const int* __restrict__ cntI,
                                             const int* __restrict__ lists,
                                             int* __restrict__ csr_off,
                                             unsigned short* __restrict__ csr_val) {
  __shared__ int wsum[256];
  __shared__ int tot[257];
  int t = threadIdx.x;
  int base = t * 8;
  int loc[8]; int s = 0;
#pragma unroll
  for (int i = 0; i < 8; ++i) {
    int c = cntI[base + i]; if (c > 48) c = 48;
    loc[i] = s; s += c;
  }
  wsum[t] = s;
  __syncthreads();
  if (t == 0) {
    int a = 0;
    for (int i = 0; i < 256; ++i) { tot[i] = a; a += wsum[i]; }
    tot[256] = a;
  }
  __syncthreads();
  int off0 = tot[t];
#pragma unroll
  for (int i = 0; i < 8; ++i) {
    int bg = base + i;
    int o = off0 + loc[i];
    csr_off[bg] = o;
    int c = cntI[bg]; if (c > 48) c = 48;
    for (int j = 0; j < c; ++j)
      csr_val[o + j] = (unsigned short)(lists[bg * 48 + j] & 1023);
  }
  if (t == 0) csr_off[2048] = tot[256];
}

// ---------------------------------------------------------------------------
// Merged front-end, persistent-block form, CONTIGUOUS-STREAM prep:
//   blocks [0,2048):    t2ga gather (gaT), then prep
//   blocks [2048,2560): pool via CSR (x, xh), then prep
// Prep phase A (per-WAVE): one full wg row (4608 f32 = 18 KB contiguous) per
// wave, loaded as 18 sequential float4/lane — the 6.3 TB/s µbench pattern.
// Lane l holds r=0..8 at c=4l (even k) and c=4l+256 (odd k); accumulation
// order r=0..8 identical to the strided form -> bitwise-same fp16 out.
// Prep phase B: w1/w2/cw casts as float4 -> half4.
__global__ __launch_bounds__(256) void k_front(const float* __restrict__ wg,
                                               const float* __restrict__ w1,
                                               const float* __restrict__ w2,
                                               const float* __restrict__ cw,
                                               _Float16* __restrict__ wgh,
                                               _Float16* __restrict__ w1h,
                                               _Float16* __restrict__ w2h,
                                               _Float16* __restrict__ cwh,
                                               const float* __restrict__ adj,
                                               const int* __restrict__ cntI,
                                               const int* __restrict__ lists,
                                               float* __restrict__ gaT,
                                               const float* __restrict__ inp,
                                               const int* __restrict__ csr_off,
                                               const unsigned short* __restrict__ csr_val,
                                               float* __restrict__ x,
                                               _Float16* __restrict__ xh) {
  __shared__ __align__(16) char smem[37120];
  int bid = blockIdx.x;
  int t = threadIdx.x;
  if (bid < 2048) {
    // ---- t2ga: gaT[b,r,h,g] = sum_{m in g} sum_{n in h} adj[r,n,m] ----
    float (*ul)[1024] = (float(*)[1024])smem;          // 9*1024*4 = 36864 B
    int* lsh = (int*)(smem + 36864);                   // 48*4 = 192 B
    int b = bid >> 8, h = bid & 255;
    int cnt = cntI[b * 256 + h]; if (cnt > 48) cnt = 48;
    if (t < cnt) lsh[t] = lists[(b * 256 + h) * 48 + t];
    __syncthreads();
    float u[9][4];
#pragma unroll
    for (int r = 0; r < 9; ++r)
#pragma unroll
      for (int j = 0; j < 4; ++j) u[r][j] = 0.f;
    for (int i = 0; i < cnt; ++i) {
      const float* base = adj + ((size_t)lsh[i] << 10) + t;
#pragma unroll
      for (int r = 0; r < 9; ++r) {
        const float* p = base + (size_t)r * 1048576;
        u[r][0] += p[0];
        u[r][1] += p[256];
        u[r][2] += p[512];
        u[r][3] += p[768];
      }
    }
#pragma unroll
    for (int r = 0; r < 9; ++r)
#pragma unroll
      for (int j = 0; j < 4; ++j) ul[r][j * 256 + t] = u[r][j];
    __syncthreads();
    int g = t;
    int cg = cntI[b * 256 + g]; if (cg > 48) cg = 48;
    const int* lg = lists + (b * 256 + g) * 48;
    float s[9];
#pragma unroll
    for (int r = 0; r < 9; ++r) s[r] = 0.f;
    for (int i = 0; i < cg; ++i) {
      int m = lg[i];
#pragma unroll
      for (int r = 0; r < 9; ++r) s[r] += ul[r][m];
    }
#pragma unroll
    for (int r = 0; r < 9; ++r)
      gaT[(((size_t)(b * 9 + r)) * 256 + h) * 256 + g] = s[r];
  } else {
    // ---- pool via CSR; emits x (f32) and fp16 cast ----
    float (*rows)[1032] = (float(*)[1032])smem;        // 8*1032*4 = 33024 B
    int* offs = (int*)(smem + 33024);                  // 257*4 = 1028 B
    unsigned short* vals = (unsigned short*)(smem + 33024 + 1028);  // 2048 B
    int blk = bid - 2048;
    int b = blk >> 6, cch = blk & 63;
    const float4* src = (const float4*)(inp + (size_t)b * 524288 + (size_t)cch * 8 * 1024);
    for (int k = t; k < 2048; k += 256) {
      float4 v = src[k];
      int c = k >> 8;
      int m = (k & 255) << 2;
      *(float4*)&rows[c][m] = v;
    }
    for (int k = t; k < 257; k += 256) offs[k] = csr_off[b * 256 + k];
    __syncthreads();
    int vbase = offs[0];
    int nv = offs[256] - vbase;
    for (int k = t; k < nv; k += 256) vals[k] = csr_val[vbase + k];
    __syncthreads();
    int g = t;
    int o0 = offs[g] - vbase, o1 = offs[g + 1] - vbase;
    float s[8] = {0.f, 0.f, 0.f, 0.f, 0.f, 0.f, 0.f, 0.f};
    for (int i = o0; i < o1; ++i) {
      int n = vals[i];
#pragma unroll
      for (int c = 0; c < 8; ++c) s[c] += rows[c][n];
    }
    const float sc = 1.0f / (1.0f + 1e-7f);
    size_t xbase = ((size_t)b * 256 + g) * 512 + cch * 8;
#pragma unroll
    for (int c = 0; c < 8; ++c) {
      float v = s[c] * sc;
      x[xbase + c] = v;
      xh[xbase + c] = (_Float16)v;
    }
  }
  // ---- prep phase A: wg collapse, one contiguous 18 KB row per wave ----
  {
    int gwave = (bid * 256 + t) >> 6;      // 0..10239
    int lane = t & 63;
    for (int row = gwave; row < 13824; row += 10240) {     // 3*4608 rows
      int i = row / 4608, j = row % 4608;
      const float4* p = (const float4*)(wg + (size_t)i * 21233664ull + (size_t)j * 4608) + lane;
      float4 v[18];
#pragma unroll
      for (int k = 0; k < 18; ++k) v[k] = p[(size_t)64 * k];
      float4 se = v[0], so = v[1];
#pragma unroll
      for (int k = 1; k < 9; ++k) {
        se.x += v[2 * k].x;     se.y += v[2 * k].y;
        se.z += v[2 * k].z;     se.w += v[2 * k].w;
        so.x += v[2 * k + 1].x; so.y += v[2 * k + 1].y;
        so.z += v[2 * k + 1].z; so.w += v[2 * k + 1].w;
      }
      half4 he, ho;
      he[0] = (_Float16)se.x; he[1] = (_Float16)se.y;
      he[2] = (_Float16)se.z; he[3] = (_Float16)se.w;
      ho[0] = (_Float16)so.x; ho[1] = (_Float16)so.y;
      ho[2] = (_Float16)so.z; ho[3] = (_Float16)so.w;
      _Float16* dst = wgh + (size_t)row * 512;
      *(half4*)(dst + 4 * lane) = he;
      *(half4*)(dst + 256 + 4 * lane) = ho;
    }
  }
  // ---- prep phase B: w1/w2/cw float4 -> half4 casts (524288 units) ----
  {
    size_t u = (size_t)bid * 256 + t;      // 655360 threads >= 524288 units
    if (u < 524288u) {
      const float4* s4; _Float16* dh; size_t o;
      if (u < 196608u)      { s4 = (const float4*)w1; dh = w1h; o = u; }
      else if (u < 393216u) { s4 = (const float4*)w2; dh = w2h; o = u - 196608u; }
      else                  { s4 = (const float4*)cw; dh = cwh; o = u - 393216u; }
      float4 v = s4[o];
      half4 hv;
      hv[0] = (_Float16)v.x; hv[1] = (_Float16)v.y;
      hv[2] = (_Float16)v.z; hv[3] = (_Float16)v.w;
      *(half4*)&dh[o * 4] = hv;
    }
  }
}

// rowsum[z,g] = sum_h gaT[z,h,g]
__global__ __launch_bounds__(256) void k_gasum(const float* __restrict__ gaT,
                                               float* __restrict__ rowsum) {
  int z = blockIdx.x;            // 72
  int t = threadIdx.x;           // g
  const float* p = gaT + ((size_t)z * 256) * 256 + t;
  float s = 0.f;
  for (int h = 0; h < 256; ++h) s += p[(size_t)h * 256];
  rowsum[z * 256 + t] = s;
}

// coef via 64x64 LDS transpose tiles; fp16.
__global__ __launch_bounds__(256) void k_coef_t(const float* __restrict__ gaT,
                                                const float* __restrict__ rowsum,
                                                _Float16* __restrict__ chi) {
  __shared__ float tl[64][65];
  __shared__ float tlf[64][65];
  __shared__ float rs[64];
  int t = threadIdx.x;
  int z = blockIdx.y;            // b*9+r
  int b = z / 9, r = z % 9;
  int tile = blockIdx.x;         // 16
  int h0 = (tile & 3) * 64, g0 = (tile >> 2) * 64;
  size_t base  = ((size_t)z * 256 + h0) * 256 + g0;
  size_t baseF = ((size_t)((7 - b) * 9 + r) * 256 + h0) * 256 + g0;
  for (int k = t; k < 4096; k += 256) {
    int i = k >> 6, j = k & 63;
    tl[i][j]  = gaT[base  + (size_t)i * 256 + j];
    tlf[i][j] = gaT[baseF + (size_t)i * 256 + j];
  }
  if (t < 64) rs[t] = rowsum[z * 256 + g0 + t] + 1.0f;
  __syncthreads();
  for (int k = t; k < 4096; k += 256) {
    int i2 = k >> 6, j2 = k & 63;        // i2: g-local, j2: h-local
    float v = tl[j2][i2], vf = tlf[j2][i2];
    float num = (r == 3) ? v : fmaxf(v - vf, 0.f);
    float c = num / rs[i2];
    size_t o = ((size_t)z * 256 + g0 + i2) * 256 + h0 + j2;
    chi[o] = (_Float16)c;
  }
}

// ---------------------------------------------------------------------------
// Final conv: fp16 GEMM, BK=64 twin subtiles, 3-buffer 2-ahead counted-vmcnt
// (6 loads/tile -> VM_BAR(6)). f32 out + bias.
__global__ __launch_bounds__(256) void k_mfma_nt1f(const _Float16* __restrict__ Ahi,
                                                   const _Float16* __restrict__ Bhi,
                                                   float* __restrict__ C,
                                                   const float* __restrict__ bias,
                                                   int M, int N, int K,
                                                   size_t Bbs, size_t Cbs) {
  __shared__ __align__(16) _Float16 Ash[3][2][128][32];
  __shared__ __align__(16) _Float16 Bsh[3][2][64][32];
  int tid = threadIdx.x;
  int z = blockIdx.z;
  const _Float16* Bh = Bhi + (size_t)z * Bbs;
  float* Cz = C + (size_t)z * Cbs;
  int bm = blockIdx.y * 128, bn = blockIdx.x * 64;
  int w = tid >> 6, lane = tid & 63;
  int wr = w >> 1, wc = w & 1;
  int l15 = lane & 15, l4 = lane >> 4;
  int rsub = lane >> 2;
  int qk = (lane & 3) * 8;
  int ar = w * 16 + rsub;
  int ar2 = ar + 64;
  f32x4 acc[4][2];
#pragma unroll
  for (int m = 0; m < 4; ++m)
#pragma unroll
    for (int n = 0; n < 2; ++n) acc[m][n] = (f32x4){0.f, 0.f, 0.f, 0.f};
  auto STG = [&](int bi, int k0) {
#pragma unroll
    for (int ks = 0; ks < 2; ++ks) {
      int kk = k0 + ks * 32;
      gll16(Ahi + (size_t)(bm + ar) * K + kk + qk,  &Ash[bi][ks][w * 16][0]);
      gll16(Ahi + (size_t)(bm + ar2) * K + kk + qk, &Ash[bi][ks][w * 16 + 64][0]);
      gll16(Bh + (size_t)(bn + ar) * K + kk + qk,   &Bsh[bi][ks][w * 16][0]);
    }
  };
  int nt = K >> 6;                  // 16
  STG(0, 0);
  STG(1, 64);
  for (int t = 0; t < nt; ++t) {
    if (t + 1 < nt) VM_BAR(6); else VM_BAR(0);
    if (t + 2 < nt) STG((t + 2) % 3, (t + 2) << 6);
    int cur = t % 3;
#pragma unroll
    for (int ks = 0; ks < 2; ++ks) {
      half8 afh[4], bfh[2];
#pragma unroll
      for (int m = 0; m < 4; ++m)
        afh[m] = *(const half8*)&Ash[cur][ks][wr * 64 + m * 16 + l15][l4 * 8];
#pragma unroll
      for (int n = 0; n < 2; ++n)
        bfh[n] = *(const half8*)&Bsh[cur][ks][wc * 32 + n * 16 + l15][l4 * 8];
#pragma unroll
      for (int m = 0; m < 4; ++m)
#pragma unroll
        for (int n = 0; n < 2; ++n)
          acc[m][n] = __builtin_amdgcn_mfma_f32_16x16x32_f16(afh[m], bfh[n], acc[m][n], 0, 0, 0);
    }
  }
#pragma unroll
  for (int m = 0; m < 4; ++m)
#pragma unroll
    for (int n = 0; n < 2; ++n)
#pragma unroll
      for (int rr = 0; rr < 4; ++rr) {
        int row = bm + wr * 64 + m * 16 + l4 * 4 + rr;
        int col = bn + wc * 32 + n * 16 + l15;
        float v = acc[m][n][rr];
        if (bias) v += bias[row];
        Cz[(size_t)row * N + col] = v;
      }
}

// ---------------------------------------------------------------------------
// dense1/dense2: fp16 GEMM, 64x64 tile, BK=64 twin subtiles, fp16 out.
// 3-buffer, 2-ahead prefetch with counted vmcnt (4 loads/tile -> VM_BAR(4)).
__global__ __launch_bounds__(256) void k_mfma_nt1f_64(const _Float16* __restrict__ Ahi,
                                                      const _Float16* __restrict__ Bhi,
                                                      _Float16* __restrict__ C,
                                                      int M, int N, int K) {
  __shared__ __align__(16) _Float16 Ash[3][2][64][32];
  __shared__ __align__(16) _Float16 Bsh[3][2][64][32];
  int tid = threadIdx.x;
  int bm = blockIdx.y * 64, bn = blockIdx.x * 64;
  int w = tid >> 6, lane = tid & 63;
  int wr = w >> 1, wc = w & 1;
  int l15 = lane & 15, l4 = lane >> 4;
  int rsub = lane >> 2;
  int qk = (lane & 3) * 8;
  int ar = w * 16 + rsub;
  f32x4 acc[2][2];
#pragma unroll
  for (int m = 0; m < 2; ++m)
#pragma unroll
    for (int n = 0; n < 2; ++n) acc[m][n] = (f32x4){0.f, 0.f, 0.f, 0.f};
  auto STG = [&](int bi, int k0) {
#pragma unroll
    for (int ks = 0; ks < 2; ++ks) {
      int kk = k0 + ks * 32;
      gll16(Ahi + (size_t)(bm + ar) * K + kk + qk, &Ash[bi][ks][w * 16][0]);
      gll16(Bhi + (size_t)(bn + ar) * K + kk + qk, &Bsh[bi][ks][w * 16][0]);
    }
  };
  int nt = K >> 6;                  // 8
  STG(0, 0);
  STG(1, 64);
  for (int t = 0; t < nt; ++t) {
    if (t + 1 < nt) VM_BAR(4); else VM_BAR(0);
    if (t + 2 < nt) STG((t + 2) % 3, (t + 2) << 6);
    int cur = t % 3;
#pragma unroll
    for (int ks = 0; ks < 2; ++ks) {
      half8 afh[2], bfh[2];
#pragma unroll
      for (int m = 0; m < 2; ++m)
        afh[m] = *(const half8*)&Ash[cur][ks][wr * 32 + m * 16 + l15][l4 * 8];
#pragma unroll
      for (int n = 0; n < 2; ++n)
        bfh[n] = *(const half8*)&Bsh[cur][ks][wc * 32 + n * 16 + l15][l4 * 8];
#pragma unroll
      for (int m = 0; m < 2; ++m)
#pragma unroll
        for (int n = 0; n < 2; ++n)
          acc[m][n] = __builtin_amdgcn_mfma_f32_16x16x32_f16(afh[m], bfh[n], acc[m][n], 0, 0, 0);
    }
  }
#pragma unroll
  for (int m = 0; m < 2; ++m)
#pragma unroll
    for (int n = 0; n < 2; ++n)
#pragma unroll
      for (int rr = 0; rr < 4; ++rr) {
        int row = bm + wr * 32 + m * 16 + l4 * 4 + rr;
        int col = bn + wc * 32 + n * 16 + l15;
        C[(size_t)row * N + col] = (_Float16)acc[m][n][rr];
      }
}

// ---------------------------------------------------------------------------
// 128x128-tile graph conv: plain fp16 GEMM, BK=32 double-buffer (32 KB LDS ->
// 5 blocks/CU; all 576 blocks co-resident), fp16 out.
__global__ __launch_bounds__(256) void k_mfma_nt1f_128(const _Float16* __restrict__ Ahi,
                                                       const _Float16* __restrict__ Bhi,
                                                       _Float16* __restrict__ C,
                                                       int M, int N, int K) {
  __shared__ __align__(16) _Float16 Ash[2][128][32];
  __shared__ __align__(16) _Float16 Bsh[2][128][32];
  int tid = threadIdx.x;
  int bm = blockIdx.y * 128, bn = blockIdx.x * 128;
  int w = tid >> 6, lane = tid & 63;
  int wr = w >> 1, wc = w & 1;
  int l15 = lane & 15, l4 = lane >> 4;
  int rsub = lane >> 2;
  int qk = (lane & 3) * 8;
  int ar = w * 16 + rsub;
  int ar2 = ar + 64;
  f32x4 acc[4][4];
#pragma unroll
  for (int m = 0; m < 4; ++m)
#pragma unroll
    for (int n = 0; n < 4; ++n) acc[m][n] = (f32x4){0.f, 0.f, 0.f, 0.f};
  auto STG = [&](int bi, int k0) {
    gll16(Ahi + (size_t)(bm + ar) * K + k0 + qk,  &Ash[bi][w * 16][0]);
    gll16(Ahi + (size_t)(bm + ar2) * K + k0 + qk, &Ash[bi][w * 16 + 64][0]);
    gll16(Bhi + (size_t)(bn + ar) * K + k0 + qk,  &Bsh[bi][w * 16][0]);
    gll16(Bhi + (size_t)(bn + ar2) * K + k0 + qk, &Bsh[bi][w * 16 + 64][0]);
  };
  int nt = K >> 5;
  STG(0, 0);
  int cur = 0;
  for (int t = 0; t < nt; ++t, cur ^= 1) {
    __syncthreads();
    if (t + 1 < nt) STG(cur ^ 1, (t + 1) << 5);
    half8 afh[4], bfh[4];
#pragma unroll
    for (int m = 0; m < 4; ++m)
      afh[m] = *(const half8*)&Ash[cur][wr * 64 + m * 16 + l15][l4 * 8];
#pragma unroll
    for (int n = 0; n < 4; ++n)
      bfh[n] = *(const half8*)&Bsh[cur][wc * 64 + n * 16 + l15][l4 * 8];
#pragma unroll
    for (int m = 0; m < 4; ++m)
#pragma unroll
      for (int n = 0; n < 4; ++n)
        acc[m][n] = __builtin_amdgcn_mfma_f32_16x16x32_f16(afh[m], bfh[n], acc[m][n], 0, 0, 0);
  }
#pragma unroll
  for (int m = 0; m < 4; ++m)
#pragma unroll
    for (int n = 0; n < 4; ++n)
#pragma unroll
      for (int rr = 0; rr < 4; ++rr) {
        int row = bm + wr * 64 + m * 16 + l4 * 4 + rr;
        int col = bn + wc * 64 + n * 16 + l15;
        C[(size_t)row * N + col] = (_Float16)acc[m][n][rr];
      }
}

// ---------------------------------------------------------------------------
// Transpose e (fp16) -> eT (fp16). Pure layout shuttle.
__global__ __launch_bounds__(256) void k_eT_split(const _Float16* __restrict__ e,
                                                  _Float16* __restrict__ eth) {
  __shared__ _Float16 tl[64][72];
  int t = threadIdx.x;
  int z = blockIdx.z;          // b*9+r
  int b = z / 9, r = z % 9;
  int h0 = blockIdx.y * 64, c0 = blockIdx.x * 64;
  const _Float16* ez = e + (size_t)b * 1179648 + (size_t)r * 131072;
  for (int k = t; k < 4096; k += 256) {
    int i = k >> 6, j = k & 63;
    tl[i][j] = ez[(size_t)(h0 + i) * 512 + c0 + j];
  }
  __syncthreads();
  for (int k = t; k < 4096; k += 256) {
    int i = k >> 6, j = k & 63;          // i: c-local, j: h-local
    size_t o = ((size_t)z * 512 + c0 + i) * 256 + h0 + j;
    eth[o] = tl[j][i];
  }
}

// ---------------------------------------------------------------------------
// h2[b,g,c] = sum_r sum_h coef[b,r,g,h] * eT[b,r,c,h] — fp16 GEMM, 64x64
// tile, BK=64 twin subtiles, 36 steps, 3-buffer 2-ahead counted-vmcnt.
__global__ __launch_bounds__(256) void k_einsum_mfma(const _Float16* __restrict__ Ahi,
                                                     const _Float16* __restrict__ Bhi,
                                                     _Float16* __restrict__ h2) {
  __shared__ __align__(16) _Float16 Ash[3][2][64][32];
  __shared__ __align__(16) _Float16 Bsh[3][2][64][32];
  int tid = threadIdx.x;
  int b = blockIdx.z;
  int bm = blockIdx.y * 64, bn = blockIdx.x * 64;
  int w = tid >> 6, lane = tid & 63;
  int wr = w >> 1, wc = w & 1;
  int l15 = lane & 15, l4 = lane >> 4;
  int rsub = lane >> 2;
  int qk = (lane & 3) * 8;
  int ar = w * 16 + rsub;
  f32x4 acc[2][2];
#pragma unroll
  for (int m = 0; m < 2; ++m)
#pragma unroll
    for (int n = 0; n < 2; ++n) acc[m][n] = (f32x4){0.f, 0.f, 0.f, 0.f};
  auto STG = [&](int bi, int kk) {
    int r = kk >> 2, k0 = (kk & 3) << 6;
    const _Float16* Ah = Ahi + ((size_t)b * 9 + r) * 65536 + (size_t)(bm + ar) * 256 + k0 + qk;
    const _Float16* Bh = Bhi + ((size_t)b * 9 + r) * 131072 + (size_t)(bn + ar) * 256 + k0 + qk;
#pragma unroll
    for (int ks = 0; ks < 2; ++ks) {
      gll16(Ah + ks * 32, &Ash[bi][ks][w * 16][0]);
      gll16(Bh + ks * 32, &Bsh[bi][ks][w * 16][0]);
    }
  };
  STG(0, 0);
  STG(1, 1);
  for (int kk = 0; kk < 36; ++kk) {
    if (kk + 1 < 36) VM_BAR(4); else VM_BAR(0);
    if (kk + 2 < 36) STG((kk + 2) % 3, kk + 2);
    int cur = kk % 3;
#pragma unroll
    for (int ks = 0; ks < 2; ++ks) {
      half8 afh[2], bfh[2];
#pragma unroll
      for (int m = 0; m < 2; ++m)
        afh[m] = *(const half8*)&Ash[cur][ks][wr * 32 + m * 16 + l15][l4 * 8];
#pragma unroll
      for (int n = 0; n < 2; ++n)
        bfh[n] = *(const half8*)&Bsh[cur][ks][wc * 32 + n * 16 + l15][l4 * 8];
#pragma unroll
      for (int m = 0; m < 2; ++m)
#pragma unroll
        for (int n = 0; n < 2; ++n)
          acc[m][n] = __builtin_amdgcn_mfma_f32_16x16x32_f16(afh[m], bfh[n], acc[m][n], 0, 0, 0);
    }
  }
#pragma unroll
  for (int m = 0; m < 2; ++m)
#pragma unroll
    for (int n = 0; n < 2; ++n)
#pragma unroll
      for (int rr = 0; rr < 4; ++rr) {
        int row = bm + wr * 32 + m * 16 + l4 * 4 + rr;
        int col = bn + wc * 32 + n * 16 + l15;
        h2[(size_t)b * 131072 + (size_t)row * 512 + col] = (_Float16)acc[m][n][rr];
      }
}

// ---------------------------------------------------------------------------
// Fused BatchNorm1d over fp16 h: wave-shfl f64 stats (2 barriers) +
// apply(+residual) + relu + fp16 out. Residual x stays f32.
__global__ __launch_bounds__(256) void k_bn_fused(const _Float16* __restrict__ h,
                                                  const float* __restrict__ gamma,
                                                  const float* __restrict__ beta,
                                                  float* __restrict__ x,
                                                  _Float16* __restrict__ ohi,
                                                  int res) {
  __shared__ double ls[4], lq[4];
  __shared__ float bc[2];
  int g = blockIdx.x;
  int tid = threadIdx.x;
  int w = tid >> 6, lane = tid & 63;
  float v[16];
  double s = 0.0, q = 0.0;
#pragma unroll
  for (int i = 0; i < 16; ++i) {
    int idx = i * 256 + tid;
    int bb = idx >> 9, c = idx & 511;
    float f = (float)h[((size_t)(bb * 256 + g) << 9) + c];
    v[i] = f;
    double d = (double)f;
    s += d; q += d * d;
  }
#pragma unroll
  for (int off = 32; off; off >>= 1) {
    s += __shfl_down(s, off, 64);
    q += __shfl_down(q, off, 64);
  }
  if (lane == 0) { ls[w] = s; lq[w] = q; }
  __syncthreads();
  if (tid == 0) {
    double st = ls[0] + ls[1] + ls[2] + ls[3];
    double qt = lq[0] + lq[1] + lq[2] + lq[3];
    double mean = st * (1.0 / 4096.0);
    double var = qt * (1.0 / 4096.0) - mean * mean;
    if (var < 0.0) var = 0.0;
    float rstd = (float)rsqrt(var + 1e-5);
    float a = gamma[g] * rstd;
    bc[0] = a;
    bc[1] = beta[g] - (float)mean * a;
  }
  __syncthreads();
  float a = bc[0], b2 = bc[1];
#pragma unroll
  for (int i = 0; i < 16; ++i) {
    int idx = i * 256 + tid;
    int bb = idx >> 9, c = idx & 511;
    size_t o = ((size_t)(bb * 256 + g) << 9) + c;
    float y = fmaf(v[i], a, b2);
    if (res) y += x[o];
    y = fmaxf(y, 0.f);
    if (res) x[o] = y;
    ohi[o] = (_Float16)y;
  }
}

// ---------------------------------------------------------------------------
// Build xcatT[b][p][c] fp16. z=0: unpool scramble of x (c<512);
// z=1: inp^T (c>=512).
__global__ __launch_bounds__(256) void k_xcatT(const float* __restrict__ x,
                                               const int* __restrict__ cntI,
                                               const int* __restrict__ gl,
                                               const float* __restrict__ inp,
                                               _Float16* __restrict__ xch) {
  __shared__ float tl[64][65];
  __shared__ int lab[1024];
  __shared__ float ic[256];
  int t = threadIdx.x;
  int b = blockIdx.y, p0 = blockIdx.x * 64;
  if (blockIdx.z == 0) {
    for (int k = t; k < 1024; k += 256) lab[k] = gl[b * 1024 + k];
    if (t < 256) ic[t] = 1.0f / ((float)cntI[b * 256 + t] + 1e-7f);
    __syncthreads();
    for (int pp = 0; pp < 64; ++pp) {
      int p = p0 + pp;
      int p9 = p >> 9, c2 = p & 511;
      const float* xb = x + (size_t)b * 131072 + c2;
      size_t obase = ((size_t)b * 1024 + p) * 1024;
#pragma unroll
      for (int ch = 0; ch < 512; ch += 256) {
        int c = ch + t;
        int g = lab[2 * c + p9];
        xch[obase + c] = (_Float16)(xb[(size_t)g * 512] * ic[g]);
      }
    }
  } else {
    for (int ct = 0; ct < 512; ct += 64) {
      __syncthreads();
      for (int k = t; k < 4096; k += 256) {
        int i = k >> 6, j = k & 63;
        tl[i][j] = inp[(size_t)b * 524288 + (size_t)(ct + i) * 1024 + p0 + j];
      }
      __syncthreads();
      for (int k = t; k < 4096; k += 256) {
        int i = k >> 6, j = k & 63;
        size_t o = ((size_t)b * 1024 + p0 + i) * 1024 + 512 + ct + j;
        xch[o] = (_Float16)tl[j][i];
      }
    }
  }
}

// ---------------------------------------------------------------------------
extern "C" void kernel_launch(void* const* d_in, const int* in_sizes, int n_in,
                              void* d_out, int out_size, void* d_ws, size_t ws_size,
                              hipStream_t stream) {
  const float* inp   = (const float*)d_in[0];
  const int*   gl    = (const int*)d_in[1];
  const float* adj   = (const float*)d_in[2];
  const float* w1    = (const float*)d_in[3];
  const float* wg    = (const float*)d_in[4];
  const float* w2    = (const float*)d_in[5];
  const float* bng   = (const float*)d_in[6];
  const float* bnb   = (const float*)d_in[7];
  const float* convw = (const float*)d_in[8];
  const float* convb = (const float*)d_in[9];
  float* out = (float*)d_out;
  float* ws = (float*)d_ws;

  _Float16* wgchi = (_Float16*)(ws + OFF_WGCH);
  _Float16* coefhi = (_Float16*)(ws + OFF_COEFH);
  float* rowsum = ws + OFF_COEF;
  float* x     = ws + OFF_X;
  int*   cntI  = (int*)(ws + OFF_CNTI);
  int*   lists = (int*)(ws + OFF_LISTS);
  int*   csrO  = (int*)(ws + OFF_CSRO);
  unsigned short* csrV = (unsigned short*)(ws + OFF_CSRV);
  _Float16* w1hi = (_Float16*)(ws + OFF_W1H);
  _Float16* w2hi = (_Float16*)(ws + OFF_W2H);
  _Float16* cwhi = (_Float16*)(ws + OFF_CWH);
  _Float16* xhi  = (_Float16*)(ws + OFF_XH);
  _Float16* hhi  = (_Float16*)(ws + OFF_HH);
  _Float16* e_h  = (_Float16*)(ws + OFF_BIG);                 // 9437184 halfs
  _Float16* eth  = (_Float16*)(ws + OFF_BIG + 4718592);       // 9437184 halfs
  _Float16* xch  = (_Float16*)(ws + OFF_BIG);                 // aliases e_h (loop done)
  float* gaT = ws + OFF_GA;
  _Float16* h1h = (_Float16*)(ws + OFF_H1);
  _Float16* h2h = (_Float16*)(ws + OFF_H2);

  hipMemsetAsync(cntI, 0, 2048 * 4, stream);

  k_lists<<<32, 256, 0, stream>>>(gl, cntI, lists);
  k_csr<<<1, 256, 0, stream>>>(cntI, lists, csrO, csrV);
  // Merged front-end, persistent blocks, contiguous-stream wg collapse.
  k_front<<<2560, 256, 0, stream>>>(wg, w1, w2, convw, wgchi, w1hi, w2hi, cwhi,
                                    adj, cntI, lists, gaT,
                                    inp, csrO, csrV, x, xhi);
  k_gasum<<<72, 256, 0, stream>>>(gaT, rowsum);
  k_coef_t<<<dim3(16, 72), 256, 0, stream>>>(gaT, rowsum, coefhi);

  for (int i = 0; i < 3; ++i) {
    // dense1: h1 = x @ w1^T  (fp16, 64x64, BK=64, 2-ahead counted-vmcnt)
    k_mfma_nt1f_64<<<dim3(8, 32), 256, 0, stream>>>(xhi, w1hi + (size_t)i * 262144,
        h1h, 2048, 512, 512);
    k_bn_fused<<<256, 256, 0, stream>>>(h1h, bng + (i * 3 + 0) * 256, bnb + (i * 3 + 0) * 256,
        nullptr, hhi, 0);
    // graph conv: e = h @ wgc^T  (fp16, BK=32 double-buffer, 5 blocks/CU)
    k_mfma_nt1f_128<<<dim3(36, 16), 256, 0, stream>>>(hhi, wgchi + (size_t)i * 2359296,
        e_h, 2048, 4608, 512);
    // coef einsum via MFMA (fp16, 64x64, BK=64, 2-ahead counted-vmcnt)
    k_eT_split<<<dim3(8, 4, 72), 256, 0, stream>>>(e_h, eth);
    k_einsum_mfma<<<dim3(8, 4, 8), 256, 0, stream>>>(coefhi, eth, h2h);
    k_bn_fused<<<256, 256, 0, stream>>>(h2h, bng + (i * 3 + 1) * 256, bnb + (i * 3 + 1) * 256,
        nullptr, hhi, 0);
    // dense2: h1 = h @ w2^T
    k_mfma_nt1f_64<<<dim3(8, 32), 256, 0, stream>>>(hhi, w2hi + (size_t)i * 262144,
        h1h, 2048, 512, 512);
    k_bn_fused<<<256, 256, 0, stream>>>(h1h, bng + (i * 3 + 2) * 256, bnb + (i * 3 + 2) * 256,
        x, xhi, 1);
  }

  k_xcatT<<<dim3(16, 8, 2), 256, 0, stream>>>(x, cntI, gl, inp, xch);
  // out[b] = convw @ xcatT[b]^T + bias  (fp16, BK=64, counted-vmcnt, f32 out)
  k_mfma_nt1f<<<dim3(16, 4, 8), 256, 0, stream>>>(cwhi, xch, out, convb,
      512, 1024, 1024, 1048576, 524288);
}